// Round 5
// baseline (224.734 us; speedup 1.0000x reference)
//
#include <hip/hip_runtime.h>
#include <hip/hip_bf16.h>

#define D_ 1024
#define H_ 16
#define FF_ 2048
#define B_ 8
#define S_ 1027
#define BS_ 8216     /* B_*S_ */
#define MPAD_ 8320   /* 130 * 64 */
#define PSTR_ 1056   /* padded key stride for P */
#define EPS_ 1e-5f
#define MAXGRID_ 512
#define NTILE_ 130

/* workspace offsets */
#define OFF_SEQ  0
#define OFF_RTHI 17039360
#define OFF_RTLO 17072128
#define OFF_S    17104896
#define OFF_P    17637376
#define OFF_CBAR 17907712   /* single 524288 buffer now */
#define OFF_O0   20004864
#define OFF_ATT  20037632
#define OFF_F1   20070400
#define OFF_F2   20103168
#define OFF_BAR  20135936
#define OFF_Q0S  20140032   /* fallback only */
#define OFF_H0   20144128   /* fallback only */

typedef __hip_bfloat16 bf16;
typedef unsigned short u16;
typedef unsigned int u32;
typedef __attribute__((ext_vector_type(4))) float floatx4;
typedef __bf16 bf16x8 __attribute__((ext_vector_type(8)));

__device__ __forceinline__ float2 bfpair(u32 u) {
  union { u32 u; float f; } lo, hi;
  lo.u = u << 16; hi.u = u & 0xffff0000u;
  return make_float2(lo.f, hi.f);
}

__device__ __forceinline__ u32 f2bfbits(float f) {
  union { bf16 h; u16 u; } cv; cv.h = __float2bfloat16(f); return (u32)cv.u;
}

// ---------------------------------------------------------------------------
// Write-through stores (sc0 sc1): bypass the non-coherent per-XCD L2s so data
// is globally visible at the MALL once vmcnt retires. Used for ALL inter-phase
// intermediates; makes the grid barrier fence-free (proven R3: 460->95us).
// ---------------------------------------------------------------------------
__device__ __forceinline__ void st_wt_f32(float* p, float v) {
  asm volatile("global_store_dword %0, %1, off sc0 sc1" :: "v"(p), "v"(v) : "memory");
}
__device__ __forceinline__ void st_wt_u16(u16* p, u32 v) {
  asm volatile("global_store_short %0, %1, off sc0 sc1" :: "v"(p), "v"(v) : "memory");
}
__device__ __forceinline__ void st_wt_v2(void* p, uint2 v) {
  asm volatile("global_store_dwordx2 %0, %1, off sc0 sc1" :: "v"(p), "v"(v) : "memory");
}
__device__ __forceinline__ void st_wt_f4(void* p, floatx4 v) {
  asm volatile("global_store_dwordx4 %0, %1, off sc0 sc1" :: "v"(p), "v"(v) : "memory");
}

// Fast block reductions: wave shuffle + 4-slot LDS combine.
__device__ __forceinline__ float blk_sum(float x, float* red) {
#pragma unroll
  for (int off = 32; off > 0; off >>= 1) x += __shfl_down(x, off, 64);
  __syncthreads();
  if ((threadIdx.x & 63) == 0) red[threadIdx.x >> 6] = x;
  __syncthreads();
  return red[0] + red[1] + red[2] + red[3];
}

__device__ __forceinline__ float blk_max(float x, float* red) {
#pragma unroll
  for (int off = 32; off > 0; off >>= 1) x = fmaxf(x, __shfl_down(x, off, 64));
  __syncthreads();
  if ((threadIdx.x & 63) == 0) red[threadIdx.x >> 6] = x;
  __syncthreads();
  return fmaxf(fmaxf(red[0], red[1]), fmaxf(red[2], red[3]));
}

// ---------------------------------------------------------------------------
// Fence-free ALL-POLL grid barrier. Arrive: relaxed bucketed add (8 buckets,
// 64B apart). Every block's t0 sums the buckets itself (no gen broadcast hop,
// saves ~1-1.5us/barrier). MUST compare >= : a fast block's next-phase arrival
// can land between two sweeps, so == could be skipped forever.
// ---------------------------------------------------------------------------
__device__ __forceinline__ void gridbar(u32* bar, u32 phase) {
  asm volatile("s_waitcnt vmcnt(0) lgkmcnt(0)" ::: "memory");
  __syncthreads();
  if (threadIdx.x == 0) {
    __hip_atomic_fetch_add(bar + (blockIdx.x & 7) * 16, 1u,
                           __ATOMIC_RELAXED, __HIP_MEMORY_SCOPE_AGENT);
    const u32 target = (u32)gridDim.x * phase;
    int spins = 0;
    for (;;) {
      u32 s = 0;
#pragma unroll
      for (int i = 0; i < 8; ++i)
        s += __hip_atomic_load(bar + i * 16, __ATOMIC_RELAXED,
                               __HIP_MEMORY_SCOPE_AGENT);
      if (s >= target) break;
      __builtin_amdgcn_s_sleep(2);
      if (++spins > 400000) break;  // safety: never hang the queue
    }
  }
  __syncthreads();
}

struct KP {
  const float *x, *y, *cls, *sep, *px, *py;
  const float *Wqkv, *bqkv, *Wo, *bo, *W1, *b1, *W2, *b2;
  const float *g1, *be1, *g2, *be2;
  const int *xl, *yl;
  bf16* seq; u16* RT_hi; u16* RT_lo; float* S; u16* P;
  float* cbar; float* o0; float* att; bf16* f1; float* f2; float* out;
  u32* bar;
};

__device__ __forceinline__ const float* row_src(const KP& p, int m,
                                                const int* lx8, const int* ly8,
                                                const float** add) {
  const int b = m / S_;
  const int s = m - b * S_;
  const int lx = lx8[b], ly = ly8[b];
  *add = nullptr;
  if (s == 0) return p.cls;
  if (s <= lx) { *add = p.px; return p.x + ((size_t)b * 512 + (s - 1)) * D_; }
  if (s == lx + 1) return p.sep;
  if (s <= lx + ly + 1) { *add = p.py; return p.y + ((size_t)b * 512 + (s - lx - 2)) * D_; }
  if (s == lx + ly + 2) return p.sep;
  return nullptr;
}

// ===========================================================================
// MEGA KERNEL v5: 9 phases, 8 all-poll barriers, pipelined build,
// atomic single-buffer cbar.
// ===========================================================================
__global__ void __launch_bounds__(256, 2) mega_kernel(KP p) {
  __shared__ __align__(16) char smem_[33792];
  const int t = threadIdx.x;
  const int bid = blockIdx.x;
  const int G = gridDim.x;

  // Entry: per-block acquire fence drops stale (poisoned) cache lines before
  // this block's first workspace READ (which only happens after gridbar(1)).
  // No cross-block ordering needed -> no entry grid barrier.
  if (t == 0) __builtin_amdgcn_fence(__ATOMIC_ACQUIRE, "agent");
  __syncthreads();

  // ---- P1: rproj (inline qproj) on blocks 0..63 || build_seq (2-deep) ----
  if (bid < 64) {
    const int h = bid >> 2, cc = bid & 3;
    float* cl = (float*)smem_;
    float* qs = (float*)(smem_ + 4096);
    *(float4*)&cl[t * 4] = ((const float4*)p.cls)[t];
    __syncthreads();
    const int r = t >> 2, j = t & 3;
    const float* wr = p.Wqkv + (size_t)(h * 64 + r) * D_;
    float acc = 0.f;
#pragma unroll 8
    for (int i = 0; i < 64; ++i) {
      float4 wv = *(const float4*)(wr + i * 16 + j * 4);
      const float* c4 = &cl[i * 16 + j * 4];
      acc += wv.x * c4[0] + wv.y * c4[1] + wv.z * c4[2] + wv.w * c4[3];
    }
    acc += __shfl_xor(acc, 1, 64);
    acc += __shfl_xor(acc, 2, 64);
    if (j == 0) qs[r] = (acc + p.bqkv[h * 64 + r]) * 0.125f;
    __syncthreads();
    const int c = cc * 256 + t;
    const float* Wk = p.Wqkv + (size_t)(D_ + h * 64) * D_ + c;
    float a2 = 0.f;
#pragma unroll 8
    for (int e = 0; e < 64; ++e) a2 += Wk[(size_t)e * D_] * qs[e];
    const u32 hb = f2bfbits(a2);
    union { u32 u; float f; } hv; hv.u = hb << 16;
    st_wt_u16(p.RT_hi + h * D_ + c, hb);
    st_wt_u16(p.RT_lo + h * D_ + c, f2bfbits(a2 - hv.f));
  } else {
    int lx8[8], ly8[8];
#pragma unroll
    for (int b = 0; b < 8; ++b) { lx8[b] = p.xl[b]; ly8[b] = p.yl[b]; }
    const int stride = G - 64;
    for (int m0 = bid - 64; m0 < BS_; m0 += 2 * stride) {
      const int m1 = m0 + stride;
      const float *ad0, *ad1 = nullptr;
      const float* s0 = row_src(p, m0, lx8, ly8, &ad0);
      const float* s1 = (m1 < BS_) ? row_src(p, m1, lx8, ly8, &ad1) : nullptr;
      float4 v0, a0v, v1, a1v;
      if (s0) v0 = ((const float4*)s0)[t];
      if (ad0) a0v = ((const float4*)ad0)[t];
      if (s1) v1 = ((const float4*)s1)[t];
      if (ad1) a1v = ((const float4*)ad1)[t];
      if (s0) {
        if (ad0) { v0.x += a0v.x; v0.y += a0v.y; v0.z += a0v.z; v0.w += a0v.w; }
        uint2 o;
        o.x = f2bfbits(v0.x) | (f2bfbits(v0.y) << 16);
        o.y = f2bfbits(v0.z) | (f2bfbits(v0.w) << 16);
        st_wt_v2((u16*)p.seq + (size_t)m0 * D_ + t * 4, o);
      }
      if (s1) {
        if (ad1) { v1.x += a1v.x; v1.y += a1v.y; v1.z += a1v.z; v1.w += a1v.w; }
        uint2 o;
        o.x = f2bfbits(v1.x) | (f2bfbits(v1.y) << 16);
        o.y = f2bfbits(v1.z) | (f2bfbits(v1.w) << 16);
        st_wt_v2((u16*)p.seq + (size_t)m1 * D_ + t * 4, o);
      }
    }
  }
  gridbar(p.bar, 1);

  // ---- P2: scores S[h][m] = seq[m,:].R[:,h] via MFMA (hi+lo) ----
  for (int wk = bid; wk < NTILE_; wk += G) {
    const int m0 = wk * 64;
    bool valid = false;
#pragma unroll
    for (int b = 0; b < B_; ++b) {
      int rs = b * S_, re = rs + p.xl[b] + p.yl[b] + 3;
      if (m0 < re && m0 + 64 > rs) valid = true;
    }
    if (!valid) continue;
    const int w = t >> 6, lane = t & 63, lane16 = lane & 15, quad = lane >> 4;
    const int row = m0 + w * 16 + lane16;
    const u16* arow = (const u16*)p.seq + (size_t)row * D_ + quad * 8;
    const u16* bh = p.RT_hi + lane16 * D_ + quad * 8;
    const u16* bl = p.RT_lo + lane16 * D_ + quad * 8;
    floatx4 acc = {};
#pragma unroll 4
    for (int kt = 0; kt < 32; ++kt) {
      bf16x8 a  = *(const bf16x8*)(arow + kt * 32);
      bf16x8 vh = *(const bf16x8*)(bh + kt * 32);
      bf16x8 vl = *(const bf16x8*)(bl + kt * 32);
      acc = __builtin_amdgcn_mfma_f32_16x16x32_bf16(a, vh, acc, 0, 0, 0);
      acc = __builtin_amdgcn_mfma_f32_16x16x32_bf16(a, vl, acc, 0, 0, 0);
    }
    st_wt_f4(&p.S[(size_t)lane16 * MPAD_ + m0 + w * 16 + quad * 4], acc);
  }
  gridbar(p.bar, 2);

  // ---- P3: softmax per (h,b) -> P (bf16) || ALL blocks zero cbar ----
  {
    // zero cbar (131072 floats = 32768 float4), write-through
    floatx4 z = {};
    for (int idx = bid * 256 + t; idx < 32768; idx += G * 256)
      st_wt_f4(p.cbar + (size_t)idx * 4, z);
  }
  for (int wk = bid; wk < 128; wk += G) {
    const int h = wk >> 3, b = wk & 7;
    const int n = p.xl[b] + p.yl[b] + 3;
    float* sc = (float*)smem_;
    float* red = (float*)(smem_ + PSTR_ * 4);
    const float* Sp = p.S + (size_t)h * MPAD_ + b * S_;
    float lmax = -3.0e38f;
    for (int k = t; k < n; k += 256) {
      float s = Sp[k];
      sc[k] = s;
      lmax = fmaxf(lmax, s);
    }
    const float gmax = blk_max(lmax, red);
    float lsum = 0.f;
    for (int k = t; k < n; k += 256) {
      float pr = __expf(sc[k] - gmax);
      sc[k] = pr;
      lsum += pr;
    }
    const float inv = 1.0f / blk_sum(lsum, red);
    u16* Pp = p.P + (size_t)(h * 8 + b) * PSTR_;
    for (int k = t; k < PSTR_; k += 256)
      st_wt_u16(Pp + k, (k < n) ? f2bfbits(sc[k] * inv) : 0u);
    __syncthreads();
  }
  gridbar(p.bar, 3);

  // ---- P4: cbar += P . seq via MFMA; K split 4-way; atomicAdd combine ----
  for (int wk = bid; wk < 512; wk += G) {
    const int ct = wk & 15, b = (wk >> 4) & 7, piece = wk >> 7;
    const int c0 = ct * 64;
    const int n = p.xl[b] + p.yl[b] + 3;
    const int nkt = (n + 31) >> 5;
    const int KR0[4] = {0, 9, 17, 25};
    const int KR1[4] = {9, 17, 25, 33};
    const int kt0 = KR0[piece];
    const int kt1 = nkt < KR1[piece] ? nkt : KR1[piece];
    u16* tile = (u16*)smem_;  // [2][32*68]
    const int w = t >> 6, lane = t & 63, lane16 = lane & 15, quad = lane >> 4;
    const int sk = t >> 3, scg = (t & 7) * 8;
    floatx4 acc = {};
    uint4 v = make_uint4(0u, 0u, 0u, 0u);
    if (kt0 < kt1 && kt0 * 32 + sk < n)
      v = *(const uint4*)((const u16*)p.seq + (size_t)((size_t)b * S_ + kt0 * 32 + sk) * D_ + c0 + scg);
    bool any = (kt0 < kt1);
    for (int kt = kt0; kt < kt1; ++kt) {
      u16* tb = tile + (kt & 1) * (32 * 68);
      *(uint2*)&tb[sk * 68 + scg]     = make_uint2(v.x, v.y);
      *(uint2*)&tb[sk * 68 + scg + 4] = make_uint2(v.z, v.w);
      v = make_uint4(0u, 0u, 0u, 0u);
      if (kt + 1 < kt1 && (kt + 1) * 32 + sk < n)
        v = *(const uint4*)((const u16*)p.seq + (size_t)((size_t)b * S_ + (kt + 1) * 32 + sk) * D_ + c0 + scg);
      __syncthreads();
      bf16x8 a = *(const bf16x8*)(p.P + (size_t)(lane16 * 8 + b) * PSTR_ + kt * 32 + quad * 8);
      union { bf16x8 v8; u16 u[8]; } bu;
#pragma unroll
      for (int j = 0; j < 8; ++j)
        bu.u[j] = tb[(quad * 8 + j) * 68 + w * 16 + lane16];
      acc = __builtin_amdgcn_mfma_f32_16x16x32_bf16(a, bu.v8, acc, 0, 0, 0);
    }
    if (any) {
#pragma unroll
      for (int r = 0; r < 4; ++r)
        atomicAdd(&p.cbar[(size_t)(b * 16 + quad * 4 + r) * D_ + c0 + w * 16 + lane16], acc[r]);
    }
    __syncthreads();
  }
  gridbar(p.bar, 4);

  // ---- P5: o0 = Wv . cbar + bv (per-head input slice) ----
  for (int wk = bid; wk < 256; wk += G) {
    float* lsf = (float*)smem_;
    const int hoff = ((wk * 4) >> 6) * D_;
#pragma unroll
    for (int i = 0; i < 8; ++i) {
      int flat = (t + i * 256) * 4;
      int b = flat >> 10, k = flat & 1023;
      *(float4*)&lsf[flat] = *(const float4*)(p.cbar + (size_t)b * 16384 + hoff + k);
    }
    __syncthreads();
    const int w = t >> 6, l = t & 63;
    const int r = wk * 4 + w;
    const float* W = p.Wqkv + (size_t)2048 * 1024;
    float acc[8] = {};
#pragma unroll
    for (int ch = 0; ch < 4; ++ch) {
      float4 wv = *(const float4*)(W + (size_t)r * D_ + ch * 256 + l * 4);
#pragma unroll
      for (int b = 0; b < 8; ++b) {
        const float* pp = &lsf[b * D_ + ch * 256 + l * 4];
        acc[b] += wv.x * pp[0] + wv.y * pp[1] + wv.z * pp[2] + wv.w * pp[3];
      }
    }
#pragma unroll
    for (int off = 32; off > 0; off >>= 1)
#pragma unroll
      for (int b = 0; b < 8; ++b) acc[b] += __shfl_down(acc[b], off, 64);
    if (l == 0) {
      const float bs = p.bqkv[2048 + r];
#pragma unroll
      for (int b = 0; b < 8; ++b) st_wt_f32(&p.o0[(size_t)b * D_ + r], acc[b] + bs);
    }
    __syncthreads();
  }
  gridbar(p.bar, 5);

  // ---- P6: att = Wo . o0 + bo ----
  for (int wk = bid; wk < 256; wk += G) {
    float* lsf = (float*)smem_;
#pragma unroll
    for (int i = 0; i < 8; ++i) {
      int flat = (t + i * 256) * 4;
      *(float4*)&lsf[flat] = *(const float4*)(p.o0 + flat);
    }
    __syncthreads();
    const int w = t >> 6, l = t & 63;
    const int r = wk * 4 + w;
    float acc[8] = {};
#pragma unroll
    for (int ch = 0; ch < 4; ++ch) {
      float4 wv = *(const float4*)(p.Wo + (size_t)r * D_ + ch * 256 + l * 4);
#pragma unroll
      for (int b = 0; b < 8; ++b) {
        const float* pp = &lsf[b * D_ + ch * 256 + l * 4];
        acc[b] += wv.x * pp[0] + wv.y * pp[1] + wv.z * pp[2] + wv.w * pp[3];
      }
    }
#pragma unroll
    for (int off = 32; off > 0; off >>= 1)
#pragma unroll
      for (int b = 0; b < 8; ++b) acc[b] += __shfl_down(acc[b], off, 64);
    if (l == 0) {
      const float bs = p.bo[r];
#pragma unroll
      for (int b = 0; b < 8; ++b) st_wt_f32(&p.att[(size_t)b * D_ + r], acc[b] + bs);
    }
    __syncthreads();
  }
  gridbar(p.bar, 6);

  // ---- P7: f1 = relu(W1 . LN1(cls+att) + b1); LN1 computed in-block ----
  for (int wk = bid; wk < 512; wk += G) {
    float* lsf = (float*)smem_;
#pragma unroll
    for (int i = 0; i < 8; ++i) {
      int flat = (t + i * 256) * 4;
      int b = flat >> 10, k = flat & 1023;
      float4 av = *(const float4*)(p.att + (size_t)b * D_ + k);
      float4 cv = *(const float4*)(p.cls + k);
      av.x += cv.x; av.y += cv.y; av.z += cv.z; av.w += cv.w;
      *(float4*)&lsf[flat] = av;
    }
    __syncthreads();
    const int w = t >> 6, l = t & 63;
#pragma unroll
    for (int bb = 2 * w; bb < 2 * w + 2; ++bb) {
      float s = 0.f;
#pragma unroll
      for (int kk = 0; kk < 16; ++kk) s += lsf[bb * 1024 + kk * 64 + l];
#pragma unroll
      for (int off = 32; off > 0; off >>= 1) s += __shfl_xor(s, off, 64);
      const float mean = s * (1.f / D_);
      float vv = 0.f;
#pragma unroll
      for (int kk = 0; kk < 16; ++kk) {
        float d = lsf[bb * 1024 + kk * 64 + l] - mean; vv += d * d;
      }
#pragma unroll
      for (int off = 32; off > 0; off >>= 1) vv += __shfl_xor(vv, off, 64);
      const float rs = rsqrtf(vv * (1.f / D_) + EPS_);
#pragma unroll
      for (int kk = 0; kk < 16; ++kk) {
        int idx = kk * 64 + l;
        lsf[bb * 1024 + idx] =
            (lsf[bb * 1024 + idx] - mean) * rs * p.g1[idx] + p.be1[idx];
      }
    }
    __syncthreads();
    const int r = wk * 4 + w;
    float acc[8] = {};
#pragma unroll
    for (int ch = 0; ch < 4; ++ch) {
      float4 wv = *(const float4*)(p.W1 + (size_t)r * D_ + ch * 256 + l * 4);
#pragma unroll
      for (int b = 0; b < 8; ++b) {
        const float* pp = &lsf[b * D_ + ch * 256 + l * 4];
        acc[b] += wv.x * pp[0] + wv.y * pp[1] + wv.z * pp[2] + wv.w * pp[3];
      }
    }
#pragma unroll
    for (int off = 32; off > 0; off >>= 1)
#pragma unroll
      for (int b = 0; b < 8; ++b) acc[b] += __shfl_down(acc[b], off, 64);
    if (l == 0) {
      const float bs = p.b1[r];
#pragma unroll
      for (int b = 0; b < 8; ++b)
        st_wt_u16((u16*)p.f1 + (size_t)b * FF_ + r, f2bfbits(fmaxf(acc[b] + bs, 0.f)));
    }
    __syncthreads();
  }
  gridbar(p.bar, 7);

  // ---- P8: f2 = W2 . f1 + b2 (bf16 in) ----
  for (int wk = bid; wk < 256; wk += G) {
    u16* lsb = (u16*)smem_;
#pragma unroll
    for (int i = 0; i < 8; ++i) {
      int flat = (t + i * 256) * 8;
      *(uint4*)&lsb[flat] = *(const uint4*)((const u16*)p.f1 + flat);
    }
    __syncthreads();
    const int w = t >> 6, l = t & 63;
    const int r = wk * 4 + w;
    float acc[8] = {};
#pragma unroll
    for (int ch = 0; ch < 8; ++ch) {
      float4 wv = *(const float4*)(p.W2 + (size_t)r * FF_ + ch * 256 + l * 4);
#pragma unroll
      for (int b = 0; b < 8; ++b) {
        uint2 u = *(const uint2*)&lsb[b * FF_ + ch * 256 + l * 4];
        float2 p0 = bfpair(u.x), p1 = bfpair(u.y);
        acc[b] += wv.x * p0.x + wv.y * p0.y + wv.z * p1.x + wv.w * p1.y;
      }
    }
#pragma unroll
    for (int off = 32; off > 0; off >>= 1)
#pragma unroll
      for (int b = 0; b < 8; ++b) acc[b] += __shfl_down(acc[b], off, 64);
    if (l == 0) {
      const float bs = p.b2[r];
#pragma unroll
      for (int b = 0; b < 8; ++b) st_wt_f32(&p.f2[(size_t)b * D_ + r], acc[b] + bs);
    }
    __syncthreads();
  }
  gridbar(p.bar, 8);

  // ---- P9: out = LN2(LN1(cls+att) + f2)  (h0 recomputed locally) ----
  for (int wk = bid; wk < 8; wk += G) {
    float* v = (float*)smem_;
    float* red = (float*)(smem_ + D_ * 4);
    for (int i = t; i < D_; i += 256) v[i] = p.cls[i] + p.att[wk * D_ + i];
    __syncthreads();
    float ls = 0.f;
    for (int i = t; i < D_; i += 256) ls += v[i];
    const float mean1 = blk_sum(ls, red) * (1.f / D_);
    float lv = 0.f;
    for (int i = t; i < D_; i += 256) { float dk = v[i] - mean1; lv += dk * dk; }
    const float var1 = blk_sum(lv, red) * (1.f / D_);
    const float rs1 = rsqrtf(var1 + EPS_);
    for (int i = t; i < D_; i += 256) {
      float h0v = (v[i] - mean1) * rs1 * p.g1[i] + p.be1[i];
      v[i] = h0v + p.f2[wk * D_ + i];
    }
    __syncthreads();
    float ls2 = 0.f;
    for (int i = t; i < D_; i += 256) ls2 += v[i];
    const float mean2 = blk_sum(ls2, red) * (1.f / D_);
    float lv2 = 0.f;
    for (int i = t; i < D_; i += 256) { float dk = v[i] - mean2; lv2 += dk * dk; }
    const float var2 = blk_sum(lv2, red) * (1.f / D_);
    const float rs2 = rsqrtf(var2 + EPS_);
    for (int i = t; i < D_; i += 256)
      p.out[wk * D_ + i] = (v[i] - mean2) * rs2 * p.g2[i] + p.be2[i];
    __syncthreads();
  }
}

// ===========================================================================
// FALLBACK: proven 13-kernel path (used only if co-residency can't be met).
// ===========================================================================
__device__ __forceinline__ float block_sum(float x, float* red) {
  const int t = threadIdx.x;
  __syncthreads();
  red[t] = x;
  __syncthreads();
  for (int s = 128; s > 0; s >>= 1) {
    if (t < s) red[t] += red[t + s];
    __syncthreads();
  }
  return red[0];
}

__device__ __forceinline__ float block_max(float x, float* red) {
  const int t = threadIdx.x;
  __syncthreads();
  red[t] = x;
  __syncthreads();
  for (int s = 128; s > 0; s >>= 1) {
    if (t < s) red[t] = fmaxf(red[t], red[t + s]);
    __syncthreads();
  }
  return red[0];
}

__global__ void __launch_bounds__(256) build_seq_kernel(
    const float* __restrict__ x, const float* __restrict__ y,
    const float* __restrict__ cls, const float* __restrict__ sep,
    const float* __restrict__ px, const float* __restrict__ py,
    const int* __restrict__ x_len, const int* __restrict__ y_len,
    bf16* __restrict__ seq) {
  const int m = blockIdx.x, t = threadIdx.x;
  const int b = m / S_;
  const int s = m - b * S_;
  if (b >= B_) return;
  const float* src = nullptr;
  const float* add = nullptr;
  const int lx = x_len[b], ly = y_len[b];
  if (s == 0) src = cls;
  else if (s <= lx) { src = x + ((size_t)b * 512 + (s - 1)) * D_; add = px; }
  else if (s == lx + 1) src = sep;
  else if (s <= lx + ly + 1) { src = y + ((size_t)b * 512 + (s - lx - 2)) * D_; add = py; }
  else if (s == lx + ly + 2) src = sep;
  if (!src) return;
  float4 sv = ((const float4*)src)[t];
  if (add) {
    float4 av = ((const float4*)add)[t];
    sv.x += av.x; sv.y += av.y; sv.z += av.z; sv.w += av.w;
  }
  uint2 o;
  o.x = f2bfbits(sv.x) | (f2bfbits(sv.y) << 16);
  o.y = f2bfbits(sv.z) | (f2bfbits(sv.w) << 16);
  ((uint2*)(seq + (size_t)m * D_))[t] = o;
}

__global__ void __launch_bounds__(256) qproj_kernel(
    const float* __restrict__ cls, const float* __restrict__ Wqkv,
    const float* __restrict__ bqkv, float* __restrict__ q0s) {
  __shared__ float cl[D_];
  const int t = threadIdx.x;
  *(float4*)&cl[t * 4] = ((const float4*)cls)[t];
  __syncthreads();
  const int w = t >> 6, l = t & 63;
  const int r = blockIdx.x * 4 + w;
  float acc = 0.f;
#pragma unroll
  for (int ch = 0; ch < 4; ++ch) {
    float4 wv = *(const float4*)(Wqkv + (size_t)r * D_ + ch * 256 + l * 4);
    const float* c4 = &cl[ch * 256 + l * 4];
    acc += wv.x * c4[0] + wv.y * c4[1] + wv.z * c4[2] + wv.w * c4[3];
  }
#pragma unroll
  for (int off = 32; off > 0; off >>= 1) acc += __shfl_down(acc, off, 64);
  if (l == 0) q0s[r] = (acc + bqkv[r]) * 0.125f;
}

__global__ void __launch_bounds__(256) rproj_kernel(
    const float* __restrict__ Wqkv, const float* __restrict__ q0s,
    u16* __restrict__ RT_hi, u16* __restrict__ RT_lo) {
  const int h = blockIdx.y, cc = blockIdx.x, t = threadIdx.x;
  __shared__ float qs[64];
  if (t < 64) qs[t] = q0s[h * 64 + t];
  __syncthreads();
  const int c = cc * 256 + t;
  const float* Wk = Wqkv + (size_t)(D_ + h * 64) * D_ + c;
  float acc = 0.f;
#pragma unroll 8
  for (int e = 0; e < 64; ++e) acc += Wk[(size_t)e * D_] * qs[e];
  const u32 hb = f2bfbits(acc);
  union { u32 u; float f; } hv; hv.u = hb << 16;
  RT_hi[h * D_ + c] = (u16)hb;
  RT_lo[h * D_ + c] = (u16)f2bfbits(acc - hv.f);
}

__global__ void __launch_bounds__(256) scores_kernel(
    const bf16* __restrict__ seq, const u16* __restrict__ RT_hi,
    const u16* __restrict__ RT_lo, const int* __restrict__ x_len,
    const int* __restrict__ y_len, float* __restrict__ S) {
  const int m0 = blockIdx.x * 64;
  bool valid = false;
#pragma unroll
  for (int b = 0; b < B_; ++b) {
    int rs = b * S_, re = rs + x_len[b] + y_len[b] + 3;
    if (m0 < re && m0 + 64 > rs) valid = true;
  }
  if (!valid) return;
  const int t = threadIdx.x;
  const int w = t >> 6, lane = t & 63, lane16 = lane & 15, quad = lane >> 4;
  const int row = m0 + w * 16 + lane16;
  const u16* arow = (const u16*)seq + (size_t)row * D_ + quad * 8;
  const u16* bh = RT_hi + lane16 * D_ + quad * 8;
  const u16* bl = RT_lo + lane16 * D_ + quad * 8;
  floatx4 acc = {};
#pragma unroll 4
  for (int kt = 0; kt < 32; ++kt) {
    bf16x8 a  = *(const bf16x8*)(arow + kt * 32);
    bf16x8 vh = *(const bf16x8*)(bh + kt * 32);
    bf16x8 vl = *(const bf16x8*)(bl + kt * 32);
    acc = __builtin_amdgcn_mfma_f32_16x16x32_bf16(a, vh, acc, 0, 0, 0);
    acc = __builtin_amdgcn_mfma_f32_16x16x32_bf16(a, vl, acc, 0, 0, 0);
  }
  *(floatx4*)&S[(size_t)lane16 * MPAD_ + m0 + w * 16 + quad * 4] = acc;
}

__global__ void __launch_bounds__(256) softmax_kernel(
    const float* __restrict__ S, const int* __restrict__ x_len,
    const int* __restrict__ y_len, u16* __restrict__ P) {
  const int h = blockIdx.x, b = blockIdx.y, t = threadIdx.x;
  const int n = x_len[b] + y_len[b] + 3;
  __shared__ float sc[PSTR_];
  __shared__ float red[256];
  const float* Sp = S + (size_t)h * MPAD_ + b * S_;
  float lmax = -3.0e38f;
  for (int k = t; k < n; k += 256) {
    float s = Sp[k];
    sc[k] = s;
    lmax = fmaxf(lmax, s);
  }
  const float gmax = block_max(lmax, red);
  float lsum = 0.f;
  for (int k = t; k < n; k += 256) {
    float p = __expf(sc[k] - gmax);
    sc[k] = p;
    lsum += p;
  }
  const float inv = 1.0f / block_sum(lsum, red);
  u16* Pp = P + (size_t)(h * 8 + b) * PSTR_;
  for (int k = t; k < PSTR_; k += 256)
    Pp[k] = (k < n) ? (u16)f2bfbits(sc[k] * inv) : (u16)0;
}

__global__ void __launch_bounds__(256) cbar_kernel(
    const bf16* __restrict__ seq, const u16* __restrict__ P,
    const int* __restrict__ x_len, const int* __restrict__ y_len,
    float* __restrict__ cbar) {
  const int ct = blockIdx.x, b = blockIdx.y, t = threadIdx.x;
  const int c0 = ct * 64;
  const int n = x_len[b] + y_len[b] + 3;
  const int nkt = (n + 31) >> 5;
  __shared__ u16 tile[32 * 68];
  const int w = t >> 6, lane = t & 63, lane16 = lane & 15, quad = lane >> 4;
  const int sk = t >> 3, scg = (t & 7) * 8;
  floatx4 acc = {};
  for (int kt = 0; kt < nkt; ++kt) {
    const int k0 = kt * 32;
    __syncthreads();
    uint4 v = make_uint4(0u, 0u, 0u, 0u);
    if (k0 + sk < n)
      v = *(const uint4*)((const u16*)seq + (size_t)(b * S_ + k0 + sk) * D_ + c0 + scg);
    *(uint2*)&tile[sk * 68 + scg]     = make_uint2(v.x, v.y);
    *(uint2*)&tile[sk * 68 + scg + 4] = make_uint2(v.z, v.w);
    __syncthreads();
    bf16x8 a = *(const bf16x8*)(P + (size_t)(lane16 * 8 + b) * PSTR_ + k0 + quad * 8);
    union { bf16x8 v; u16 u[8]; } bu;
#pragma unroll
    for (int j = 0; j < 8; ++j)
      bu.u[j] = tile[(quad * 8 + j) * 68 + w * 16 + lane16];
    acc = __builtin_amdgcn_mfma_f32_16x16x32_bf16(a, bu.v, acc, 0, 0, 0);
  }
#pragma unroll
  for (int r = 0; r < 4; ++r)
    cbar[(size_t)(b * 16 + quad * 4 + r) * D_ + c0 + w * 16 + lane16] = acc[r];
}

template <int K, int N, int BSTR, bool INBF, bool OUTBF, bool RELU, bool PERHEAD>
__global__ void __launch_bounds__(256) gemv8_kernel(
    const void* __restrict__ in_, const float* __restrict__ W,
    const float* __restrict__ bias, void* __restrict__ out_) {
  const int t = threadIdx.x;
  const int hoff = PERHEAD ? ((blockIdx.x * 4) >> 6) * D_ : 0;
  __shared__ u16 lsb[INBF ? 8 * K : 1];
  __shared__ float lsf[INBF ? 1 : 8 * K];
  if (INBF) {
    const u16* in = (const u16*)in_;
    const int per = 8 * K / (256 * 8);
#pragma unroll
    for (int i = 0; i < per; ++i) {
      int flat = (t + i * 256) * 8;
      int b = flat / K, k = flat % K;
      *(uint4*)&lsb[flat] = *(const uint4*)(in + (size_t)b * BSTR + hoff + k);
    }
  } else {
    const float* in = (const float*)in_;
    const int per = 8 * K / (256 * 4);
#pragma unroll
    for (int i = 0; i < per; ++i) {
      int flat = (t + i * 256) * 4;
      int b = flat / K, k = flat % K;
      *(float4*)&lsf[flat] = *(const float4*)(in + (size_t)b * BSTR + hoff + k);
    }
  }
  __syncthreads();
  const int w = t >> 6, l = t & 63;
  const int r = blockIdx.x * 4 + w;
  float acc[8] = {};
#pragma unroll
  for (int ch = 0; ch < K / 256; ++ch) {
    float4 wv = *(const float4*)(W + (size_t)r * K + ch * 256 + l * 4);
#pragma unroll
    for (int b = 0; b < 8; ++b) {
      float i0, i1, i2, i3;
      if (INBF) {
        uint2 u = *(const uint2*)&lsb[b * K + ch * 256 + l * 4];
        float2 p0 = bfpair(u.x), p1 = bfpair(u.y);
        i0 = p0.x; i1 = p0.y; i2 = p1.x; i3 = p1.y;
      } else {
        const float* p = &lsf[b * K + ch * 256 + l * 4];
        i0 = p[0]; i1 = p[1]; i2 = p[2]; i3 = p[3];
      }
      acc[b] += wv.x * i0 + wv.y * i1 + wv.z * i2 + wv.w * i3;
    }
  }
#pragma unroll
  for (int off = 32; off > 0; off >>= 1)
#pragma unroll
    for (int b = 0; b < 8; ++b) acc[b] += __shfl_down(acc[b], off, 64);
  if (l == 0) {
    const float bs = bias[r];
#pragma unroll
    for (int b = 0; b < 8; ++b) {
      float v = acc[b] + bs;
      if (RELU) v = fmaxf(v, 0.f);
      if (OUTBF) ((bf16*)out_)[(size_t)b * N + r] = __float2bfloat16(v);
      else       ((float*)out_)[(size_t)b * N + r] = v;
    }
  }
}

template <bool SECOND>
__global__ void __launch_bounds__(256) ln_kernel(
    const float* __restrict__ cls, const float* __restrict__ a,
    const float* __restrict__ bvec, const float* __restrict__ g,
    const float* __restrict__ be, float* __restrict__ out) {
  const int b = blockIdx.x, t = threadIdx.x;
  __shared__ float v[D_];
  __shared__ float red[256];
  for (int i = t; i < D_; i += 256) {
    float val;
    if (SECOND) val = a[b * D_ + i] + bvec[b * D_ + i];
    else        val = cls[i] + a[b * D_ + i];
    v[i] = val;
  }
  __syncthreads();
  float ls = 0.f;
  for (int i = t; i < D_; i += 256) ls += v[i];
  const float mean = block_sum(ls, red) * (1.f / D_);
  float lv = 0.f;
  for (int i = t; i < D_; i += 256) { float dk = v[i] - mean; lv += dk * dk; }
  const float var = block_sum(lv, red) * (1.f / D_);
  const float rs = rsqrtf(var + EPS_);
  for (int i = t; i < D_; i += 256)
    out[b * D_ + i] = (v[i] - mean) * rs * g[i] + be[i];
}

// ---------------------------------------------------------------------------
extern "C" void kernel_launch(void* const* d_in, const int* in_sizes, int n_in,
                              void* d_out, int out_size, void* d_ws, size_t ws_size,
                              hipStream_t stream) {
  (void)in_sizes; (void)n_in; (void)out_size; (void)ws_size;
  const float* x    = (const float*)d_in[0];
  const float* y    = (const float*)d_in[1];
  const float* cls  = (const float*)d_in[2];
  const float* sep  = (const float*)d_in[3];
  const float* px   = (const float*)d_in[4];
  const float* py   = (const float*)d_in[5];
  const float* Wqkv = (const float*)d_in[6];
  const float* bqkv = (const float*)d_in[7];
  const float* Wo   = (const float*)d_in[8];
  const float* bo   = (const float*)d_in[9];
  const float* W1   = (const float*)d_in[10];
  const float* b1   = (const float*)d_in[11];
  const float* W2   = (const float*)d_in[12];
  const float* b2   = (const float*)d_in[13];
  const float* g1   = (const float*)d_in[14];
  const float* be1  = (const float*)d_in[15];
  const float* g2   = (const float*)d_in[16];
  const float* be2  = (const float*)d_in[17];
  const int* xl     = (const int*)d_in[18];
  const int* yl     = (const int*)d_in[19];

  char* ws = (char*)d_ws;
  bf16*  seq   = (bf16*)(ws + OFF_SEQ);
  u16*   RT_hi = (u16*)(ws + OFF_RTHI);
  u16*   RT_lo = (u16*)(ws + OFF_RTLO);
  float* S     = (float*)(ws + OFF_S);
  u16*   P     = (u16*)(ws + OFF_P);
  float* cbar  = (float*)(ws + OFF_CBAR);
  float* o0    = (float*)(ws + OFF_O0);
  float* att   = (float*)(ws + OFF_ATT);
  bf16*  f1    = (bf16*)(ws + OFF_F1);
  float* f2    = (float*)(ws + OFF_F2);
  u32*   bar   = (u32*)(ws + OFF_BAR);
  float* q0s   = (float*)(ws + OFF_Q0S);
  float* h0    = (float*)(ws + OFF_H0);

  KP kp;
  kp.x = x; kp.y = y; kp.cls = cls; kp.sep = sep; kp.px = px; kp.py = py;
  kp.Wqkv = Wqkv; kp.bqkv = bqkv; kp.Wo = Wo; kp.bo = bo;
  kp.W1 = W1; kp.b1 = b1; kp.W2 = W2; kp.b2 = b2;
  kp.g1 = g1; kp.be1 = be1; kp.g2 = g2; kp.be2 = be2;
  kp.xl = xl; kp.yl = yl;
  kp.seq = seq; kp.RT_hi = RT_hi; kp.RT_lo = RT_lo;
  kp.S = S; kp.P = P; kp.cbar = cbar;
  kp.o0 = o0; kp.att = att; kp.f1 = f1; kp.f2 = f2;
  kp.out = (float*)d_out;
  kp.bar = bar;

  // Co-residency capacity check (cached). Plain launch; no cooperative API.
  static int mega_grid = -2;
  if (mega_grid == -2) {
    int nb = 0, ncu = 256;
    hipDeviceProp_t props;
    if (hipGetDeviceProperties(&props, 0) == hipSuccess)
      ncu = props.multiProcessorCount;
    if (hipOccupancyMaxActiveBlocksPerMultiprocessor(&nb, mega_kernel, 256, 0) ==
            hipSuccess && nb > 0) {
      long g = (long)nb * ncu;
      mega_grid = (int)(g < MAXGRID_ ? g : MAXGRID_);
    } else {
      mega_grid = -1;
    }
    if (mega_grid < 72) mega_grid = -1;  // P1 split needs >64 blocks
  }

  if (mega_grid > 0) {
    // zero barrier state (workspace is re-poisoned by the harness each iter)
    hipMemsetAsync(ws + OFF_BAR, 0, 4096, stream);
    mega_kernel<<<mega_grid, 256, 0, stream>>>(kp);
  } else {
    build_seq_kernel<<<MPAD_, 256, 0, stream>>>(x, y, cls, sep, px, py, xl, yl, seq);
    qproj_kernel<<<256, 256, 0, stream>>>(cls, Wqkv, bqkv, q0s);
    rproj_kernel<<<dim3(4, 16), 256, 0, stream>>>(Wqkv, q0s, RT_hi, RT_lo);
    scores_kernel<<<130, 256, 0, stream>>>(seq, RT_hi, RT_lo, xl, yl, S);
    softmax_kernel<<<dim3(16, 8), 256, 0, stream>>>(S, xl, yl, P);
    cbar_kernel<<<dim3(16, 8), 256, 0, stream>>>(seq, P, xl, yl, cbar);
    gemv8_kernel<1024, 1024, 16384, false, false, false, true>
        <<<256, 256, 0, stream>>>(cbar, Wqkv + (size_t)2048 * 1024, bqkv + 2048, o0);
    gemv8_kernel<1024, 1024, 1024, false, false, false, false>
        <<<256, 256, 0, stream>>>(o0, Wo, bo, att);
    ln_kernel<false><<<B_, 256, 0, stream>>>(cls, att, nullptr, g1, be1, h0);
    gemv8_kernel<1024, 2048, 1024, false, true, true, false>
        <<<512, 256, 0, stream>>>(h0, W1, b1, f1);
    gemv8_kernel<2048, 1024, 2048, true, false, false, false>
        <<<256, 256, 0, stream>>>(f1, W2, b2, f2);
    ln_kernel<true><<<B_, 256, 0, stream>>>(nullptr, h0, f2, g2, be2, (float*)d_out);
  }
}

// Round 6
// 204.685 us; speedup vs baseline: 1.0980x; 1.0980x over previous
//
#include <hip/hip_runtime.h>
#include <hip/hip_bf16.h>

#define D_ 1024
#define H_ 16
#define FF_ 2048
#define B_ 8
#define S_ 1027
#define BS_ 8216     /* B_*S_ */
#define MPAD_ 8320   /* 130 * 64 */
#define PSTR_ 1056   /* padded key stride for P */
#define EPS_ 1e-5f
#define MAXGRID_ 512
#define NTILE_ 130
#define NBUCK_ 32

/* workspace offsets */
#define OFF_SEQ  0
#define OFF_RTHI 17039360
#define OFF_RTLO 17072128
#define OFF_S    17104896
#define OFF_P    17637376
#define OFF_CBAR 17907712   /* 4 pieces x 524288 */
#define OFF_O0   20004864
#define OFF_ATT  20037632
#define OFF_F1   20070400
#define OFF_F2   20103168
#define OFF_BAR  20135936
#define OFF_Q0S  20140032   /* fallback only */
#define OFF_H0   20144128   /* fallback only */

typedef __hip_bfloat16 bf16;
typedef unsigned short u16;
typedef unsigned int u32;
typedef __attribute__((ext_vector_type(4))) float floatx4;
typedef __bf16 bf16x8 __attribute__((ext_vector_type(8)));

__device__ __forceinline__ float2 bfpair(u32 u) {
  union { u32 u; float f; } lo, hi;
  lo.u = u << 16; hi.u = u & 0xffff0000u;
  return make_float2(lo.f, hi.f);
}

__device__ __forceinline__ u32 f2bfbits(float f) {
  union { bf16 h; u16 u; } cv; cv.h = __float2bfloat16(f); return (u32)cv.u;
}

// ---------------------------------------------------------------------------
// Write-through stores (sc0 sc1): bypass the non-coherent per-XCD L2s so data
// is globally visible at the MALL once vmcnt retires. Used for ALL inter-phase
// intermediates; makes the grid barrier fence-free (proven R3: 460->95us).
// ---------------------------------------------------------------------------
__device__ __forceinline__ void st_wt_f32(float* p, float v) {
  asm volatile("global_store_dword %0, %1, off sc0 sc1" :: "v"(p), "v"(v) : "memory");
}
__device__ __forceinline__ void st_wt_u16(u16* p, u32 v) {
  asm volatile("global_store_short %0, %1, off sc0 sc1" :: "v"(p), "v"(v) : "memory");
}
__device__ __forceinline__ void st_wt_v2(void* p, uint2 v) {
  asm volatile("global_store_dwordx2 %0, %1, off sc0 sc1" :: "v"(p), "v"(v) : "memory");
}
__device__ __forceinline__ void st_wt_f4(void* p, floatx4 v) {
  asm volatile("global_store_dwordx4 %0, %1, off sc0 sc1" :: "v"(p), "v"(v) : "memory");
}

// Fast block reductions: wave shuffle + 4-slot LDS combine.
__device__ __forceinline__ float blk_sum(float x, float* red) {
#pragma unroll
  for (int off = 32; off > 0; off >>= 1) x += __shfl_down(x, off, 64);
  __syncthreads();
  if ((threadIdx.x & 63) == 0) red[threadIdx.x >> 6] = x;
  __syncthreads();
  return red[0] + red[1] + red[2] + red[3];
}

__device__ __forceinline__ float blk_max(float x, float* red) {
#pragma unroll
  for (int off = 32; off > 0; off >>= 1) x = fmaxf(x, __shfl_down(x, off, 64));
  __syncthreads();
  if ((threadIdx.x & 63) == 0) red[threadIdx.x >> 6] = x;
  __syncthreads();
  return fmaxf(fmaxf(red[0], red[1]), fmaxf(red[2], red[3]));
}

// ---------------------------------------------------------------------------
// Fence-free grid barrier, GEN-BROADCAST form (R4-proven: 91us kernel).
// R5's all-poll variant regressed (+8us/barrier): 512 sweepers x 8 lines of
// MALL atomic traffic contended with working phases. Here 511 blocks poll ONE
// gen line; only block0 sweeps the 32 arrival buckets. '==' is safe: arrivals
// for phase k+1 can only start after gen=k is published.
// ---------------------------------------------------------------------------
__device__ __forceinline__ void gridbar(u32* bar, u32 phase) {
  asm volatile("s_waitcnt vmcnt(0) lgkmcnt(0)" ::: "memory");
  __syncthreads();
  if (threadIdx.x == 0) {
    __hip_atomic_fetch_add(bar + (blockIdx.x & (NBUCK_ - 1)) * 16, 1u,
                           __ATOMIC_RELAXED, __HIP_MEMORY_SCOPE_AGENT);
    u32* gen = bar + NBUCK_ * 16;
    if (blockIdx.x == 0) {
      const u32 target = (u32)gridDim.x * phase;
      int spins = 0;
      for (;;) {
        u32 s = 0;
#pragma unroll
        for (int i = 0; i < NBUCK_; ++i)
          s += __hip_atomic_load(bar + i * 16, __ATOMIC_RELAXED,
                                 __HIP_MEMORY_SCOPE_AGENT);
        if (s == target) break;
        __builtin_amdgcn_s_sleep(1);
        if (++spins > 300000) break;  // safety: never hang the queue
      }
      __hip_atomic_store(gen, phase, __ATOMIC_RELAXED, __HIP_MEMORY_SCOPE_AGENT);
    } else {
      int spins = 0;
      while (__hip_atomic_load(gen, __ATOMIC_RELAXED,
                               __HIP_MEMORY_SCOPE_AGENT) < phase) {
        __builtin_amdgcn_s_sleep(2);
        if (++spins > 300000) break;  // safety
      }
    }
  }
  __syncthreads();
}

struct KP {
  const float *x, *y, *cls, *sep, *px, *py;
  const float *Wqkv, *bqkv, *Wo, *bo, *W1, *b1, *W2, *b2;
  const float *g1, *be1, *g2, *be2;
  const int *xl, *yl;
  bf16* seq; u16* RT_hi; u16* RT_lo; float* S; u16* P;
  float* cbar4; float* o0; float* att; bf16* f1; float* f2; float* out;
  u32* bar;
};

__device__ __forceinline__ const float* row_src(const KP& p, int m,
                                                const int* lx8, const int* ly8,
                                                const float** add) {
  const int b = m / S_;
  const int s = m - b * S_;
  const int lx = lx8[b], ly = ly8[b];
  *add = nullptr;
  if (s == 0) return p.cls;
  if (s <= lx) { *add = p.px; return p.x + ((size_t)b * 512 + (s - 1)) * D_; }
  if (s == lx + 1) return p.sep;
  if (s <= lx + ly + 1) { *add = p.py; return p.y + ((size_t)b * 512 + (s - lx - 2)) * D_; }
  if (s == lx + ly + 2) return p.sep;
  return nullptr;
}

// ===========================================================================
// MEGA KERNEL v6 = R4 (91us proven) minus entry grid barrier (per-block
// acquire fence suffices) plus 2-deep pipelined build. Deterministic cbar4.
// ===========================================================================
__global__ void __launch_bounds__(256, 2) mega_kernel(KP p) {
  __shared__ __align__(16) char smem_[33792];
  const int t = threadIdx.x;
  const int bid = blockIdx.x;
  const int G = gridDim.x;

  // Entry: per-block acquire fence drops stale (poisoned) cache lines before
  // this block's first workspace read. Producers store write-through, so no
  // cross-block ordering is needed for the invalidate -> no grid barrier.
  if (t == 0) __builtin_amdgcn_fence(__ATOMIC_ACQUIRE, "agent");
  __syncthreads();

  // ---- P1: rproj (inline qproj) on blocks 0..63 || build_seq (2-deep) ----
  if (bid < 64) {
    const int h = bid >> 2, cc = bid & 3;
    float* cl = (float*)smem_;
    float* qs = (float*)(smem_ + 4096);
    *(float4*)&cl[t * 4] = ((const float4*)p.cls)[t];
    __syncthreads();
    const int r = t >> 2, j = t & 3;
    const float* wr = p.Wqkv + (size_t)(h * 64 + r) * D_;
    float acc = 0.f;
#pragma unroll 8
    for (int i = 0; i < 64; ++i) {
      float4 wv = *(const float4*)(wr + i * 16 + j * 4);
      const float* c4 = &cl[i * 16 + j * 4];
      acc += wv.x * c4[0] + wv.y * c4[1] + wv.z * c4[2] + wv.w * c4[3];
    }
    acc += __shfl_xor(acc, 1, 64);
    acc += __shfl_xor(acc, 2, 64);
    if (j == 0) qs[r] = (acc + p.bqkv[h * 64 + r]) * 0.125f;
    __syncthreads();
    const int c = cc * 256 + t;
    const float* Wk = p.Wqkv + (size_t)(D_ + h * 64) * D_ + c;
    float a2 = 0.f;
#pragma unroll 8
    for (int e = 0; e < 64; ++e) a2 += Wk[(size_t)e * D_] * qs[e];
    const u32 hb = f2bfbits(a2);
    union { u32 u; float f; } hv; hv.u = hb << 16;
    st_wt_u16(p.RT_hi + h * D_ + c, hb);
    st_wt_u16(p.RT_lo + h * D_ + c, f2bfbits(a2 - hv.f));
  } else {
    int lx8[8], ly8[8];
#pragma unroll
    for (int b = 0; b < 8; ++b) { lx8[b] = p.xl[b]; ly8[b] = p.yl[b]; }
    const int stride = G - 64;
    for (int m0 = bid - 64; m0 < BS_; m0 += 2 * stride) {
      const int m1 = m0 + stride;
      const float *ad0, *ad1 = nullptr;
      const float* s0 = row_src(p, m0, lx8, ly8, &ad0);
      const float* s1 = (m1 < BS_) ? row_src(p, m1, lx8, ly8, &ad1) : nullptr;
      float4 v0, a0v, v1, a1v;
      if (s0) v0 = ((const float4*)s0)[t];
      if (ad0) a0v = ((const float4*)ad0)[t];
      if (s1) v1 = ((const float4*)s1)[t];
      if (ad1) a1v = ((const float4*)ad1)[t];
      if (s0) {
        if (ad0) { v0.x += a0v.x; v0.y += a0v.y; v0.z += a0v.z; v0.w += a0v.w; }
        uint2 o;
        o.x = f2bfbits(v0.x) | (f2bfbits(v0.y) << 16);
        o.y = f2bfbits(v0.z) | (f2bfbits(v0.w) << 16);
        st_wt_v2((u16*)p.seq + (size_t)m0 * D_ + t * 4, o);
      }
      if (s1) {
        if (ad1) { v1.x += a1v.x; v1.y += a1v.y; v1.z += a1v.z; v1.w += a1v.w; }
        uint2 o;
        o.x = f2bfbits(v1.x) | (f2bfbits(v1.y) << 16);
        o.y = f2bfbits(v1.z) | (f2bfbits(v1.w) << 16);
        st_wt_v2((u16*)p.seq + (size_t)m1 * D_ + t * 4, o);
      }
    }
  }
  gridbar(p.bar, 1);

  // ---- P2: scores S[h][m] = seq[m,:].R[:,h] via MFMA (hi+lo) ----
  for (int wk = bid; wk < NTILE_; wk += G) {
    const int m0 = wk * 64;
    bool valid = false;
#pragma unroll
    for (int b = 0; b < B_; ++b) {
      int rs = b * S_, re = rs + p.xl[b] + p.yl[b] + 3;
      if (m0 < re && m0 + 64 > rs) valid = true;
    }
    if (!valid) continue;
    const int w = t >> 6, lane = t & 63, lane16 = lane & 15, quad = lane >> 4;
    const int row = m0 + w * 16 + lane16;
    const u16* arow = (const u16*)p.seq + (size_t)row * D_ + quad * 8;
    const u16* bh = p.RT_hi + lane16 * D_ + quad * 8;
    const u16* bl = p.RT_lo + lane16 * D_ + quad * 8;
    floatx4 acc = {};
#pragma unroll 4
    for (int kt = 0; kt < 32; ++kt) {
      bf16x8 a  = *(const bf16x8*)(arow + kt * 32);
      bf16x8 vh = *(const bf16x8*)(bh + kt * 32);
      bf16x8 vl = *(const bf16x8*)(bl + kt * 32);
      acc = __builtin_amdgcn_mfma_f32_16x16x32_bf16(a, vh, acc, 0, 0, 0);
      acc = __builtin_amdgcn_mfma_f32_16x16x32_bf16(a, vl, acc, 0, 0, 0);
    }
    st_wt_f4(&p.S[(size_t)lane16 * MPAD_ + m0 + w * 16 + quad * 4], acc);
  }
  gridbar(p.bar, 2);

  // ---- P3: softmax per (h,b), normalized bf16 into P ----
  for (int wk = bid; wk < 128; wk += G) {
    const int h = wk >> 3, b = wk & 7;
    const int n = p.xl[b] + p.yl[b] + 3;
    float* sc = (float*)smem_;
    float* red = (float*)(smem_ + PSTR_ * 4);
    const float* Sp = p.S + (size_t)h * MPAD_ + b * S_;
    float lmax = -3.0e38f;
    for (int k = t; k < n; k += 256) {
      float s = Sp[k];
      sc[k] = s;
      lmax = fmaxf(lmax, s);
    }
    const float gmax = blk_max(lmax, red);
    float lsum = 0.f;
    for (int k = t; k < n; k += 256) {
      float pr = __expf(sc[k] - gmax);
      sc[k] = pr;
      lsum += pr;
    }
    const float inv = 1.0f / blk_sum(lsum, red);
    u16* Pp = p.P + (size_t)(h * 8 + b) * PSTR_;
    for (int k = t; k < PSTR_; k += 256)
      st_wt_u16(Pp + k, (k < n) ? f2bfbits(sc[k] * inv) : 0u);
    __syncthreads();
  }
  gridbar(p.bar, 3);

  // ---- P4: cbar = P . seq via MFMA; K split 4-way into 4 buffers ----
  for (int wk = bid; wk < 512; wk += G) {
    const int ct = wk & 15, b = (wk >> 4) & 7, piece = wk >> 7;
    const int c0 = ct * 64;
    const int n = p.xl[b] + p.yl[b] + 3;
    const int nkt = (n + 31) >> 5;
    const int KR0[4] = {0, 9, 17, 25};
    const int KR1[4] = {9, 17, 25, 33};
    const int kt0 = KR0[piece];
    const int kt1 = nkt < KR1[piece] ? nkt : KR1[piece];
    u16* tile = (u16*)smem_;  // [2][32*68]
    const int w = t >> 6, lane = t & 63, lane16 = lane & 15, quad = lane >> 4;
    const int sk = t >> 3, scg = (t & 7) * 8;
    floatx4 acc = {};
    uint4 v = make_uint4(0u, 0u, 0u, 0u);
    if (kt0 < kt1 && kt0 * 32 + sk < n)
      v = *(const uint4*)((const u16*)p.seq + (size_t)((size_t)b * S_ + kt0 * 32 + sk) * D_ + c0 + scg);
    for (int kt = kt0; kt < kt1; ++kt) {
      u16* tb = tile + (kt & 1) * (32 * 68);
      *(uint2*)&tb[sk * 68 + scg]     = make_uint2(v.x, v.y);
      *(uint2*)&tb[sk * 68 + scg + 4] = make_uint2(v.z, v.w);
      v = make_uint4(0u, 0u, 0u, 0u);
      if (kt + 1 < kt1 && (kt + 1) * 32 + sk < n)
        v = *(const uint4*)((const u16*)p.seq + (size_t)((size_t)b * S_ + (kt + 1) * 32 + sk) * D_ + c0 + scg);
      __syncthreads();
      bf16x8 a = *(const bf16x8*)(p.P + (size_t)(lane16 * 8 + b) * PSTR_ + kt * 32 + quad * 8);
      union { bf16x8 v8; u16 u[8]; } bu;
#pragma unroll
      for (int j = 0; j < 8; ++j)
        bu.u[j] = tb[(quad * 8 + j) * 68 + w * 16 + lane16];
      acc = __builtin_amdgcn_mfma_f32_16x16x32_bf16(a, bu.v8, acc, 0, 0, 0);
    }
    float* dst = p.cbar4 + (size_t)piece * 131072;
#pragma unroll
    for (int r = 0; r < 4; ++r)
      st_wt_f32(&dst[(size_t)(b * 16 + quad * 4 + r) * D_ + c0 + w * 16 + lane16], acc[r]);
    __syncthreads();
  }
  gridbar(p.bar, 4);

  // ---- P5: o0 = Wv . (sum of 4 cbar pieces) + bv (per-head input slice) ----
  for (int wk = bid; wk < 256; wk += G) {
    float* lsf = (float*)smem_;
    const int hoff = ((wk * 4) >> 6) * D_;
#pragma unroll
    for (int i = 0; i < 8; ++i) {
      int flat = (t + i * 256) * 4;
      int b = flat >> 10, k = flat & 1023;
      size_t off = (size_t)b * 16384 + hoff + k;
      float4 a0 = *(const float4*)(p.cbar4 + off);
      float4 a1 = *(const float4*)(p.cbar4 + 131072 + off);
      float4 a2 = *(const float4*)(p.cbar4 + 262144 + off);
      float4 a3 = *(const float4*)(p.cbar4 + 393216 + off);
      a0.x += a1.x + a2.x + a3.x; a0.y += a1.y + a2.y + a3.y;
      a0.z += a1.z + a2.z + a3.z; a0.w += a1.w + a2.w + a3.w;
      *(float4*)&lsf[flat] = a0;
    }
    __syncthreads();
    const int w = t >> 6, l = t & 63;
    const int r = wk * 4 + w;
    const float* W = p.Wqkv + (size_t)2048 * 1024;
    float acc[8] = {};
#pragma unroll
    for (int ch = 0; ch < 4; ++ch) {
      float4 wv = *(const float4*)(W + (size_t)r * D_ + ch * 256 + l * 4);
#pragma unroll
      for (int b = 0; b < 8; ++b) {
        const float* pp = &lsf[b * D_ + ch * 256 + l * 4];
        acc[b] += wv.x * pp[0] + wv.y * pp[1] + wv.z * pp[2] + wv.w * pp[3];
      }
    }
#pragma unroll
    for (int off = 32; off > 0; off >>= 1)
#pragma unroll
      for (int b = 0; b < 8; ++b) acc[b] += __shfl_down(acc[b], off, 64);
    if (l == 0) {
      const float bs = p.bqkv[2048 + r];
#pragma unroll
      for (int b = 0; b < 8; ++b) st_wt_f32(&p.o0[(size_t)b * D_ + r], acc[b] + bs);
    }
    __syncthreads();
  }
  gridbar(p.bar, 5);

  // ---- P6: att = Wo . o0 + bo ----
  for (int wk = bid; wk < 256; wk += G) {
    float* lsf = (float*)smem_;
#pragma unroll
    for (int i = 0; i < 8; ++i) {
      int flat = (t + i * 256) * 4;
      *(float4*)&lsf[flat] = *(const float4*)(p.o0 + flat);
    }
    __syncthreads();
    const int w = t >> 6, l = t & 63;
    const int r = wk * 4 + w;
    float acc[8] = {};
#pragma unroll
    for (int ch = 0; ch < 4; ++ch) {
      float4 wv = *(const float4*)(p.Wo + (size_t)r * D_ + ch * 256 + l * 4);
#pragma unroll
      for (int b = 0; b < 8; ++b) {
        const float* pp = &lsf[b * D_ + ch * 256 + l * 4];
        acc[b] += wv.x * pp[0] + wv.y * pp[1] + wv.z * pp[2] + wv.w * pp[3];
      }
    }
#pragma unroll
    for (int off = 32; off > 0; off >>= 1)
#pragma unroll
      for (int b = 0; b < 8; ++b) acc[b] += __shfl_down(acc[b], off, 64);
    if (l == 0) {
      const float bs = p.bo[r];
#pragma unroll
      for (int b = 0; b < 8; ++b) st_wt_f32(&p.att[(size_t)b * D_ + r], acc[b] + bs);
    }
    __syncthreads();
  }
  gridbar(p.bar, 6);

  // ---- P7: f1 = relu(W1 . LN1(cls+att) + b1); LN1 computed in-block ----
  for (int wk = bid; wk < 512; wk += G) {
    float* lsf = (float*)smem_;
#pragma unroll
    for (int i = 0; i < 8; ++i) {
      int flat = (t + i * 256) * 4;
      int b = flat >> 10, k = flat & 1023;
      float4 av = *(const float4*)(p.att + (size_t)b * D_ + k);
      float4 cv = *(const float4*)(p.cls + k);
      av.x += cv.x; av.y += cv.y; av.z += cv.z; av.w += cv.w;
      *(float4*)&lsf[flat] = av;
    }
    __syncthreads();
    const int w = t >> 6, l = t & 63;
#pragma unroll
    for (int bb = 2 * w; bb < 2 * w + 2; ++bb) {
      float s = 0.f;
#pragma unroll
      for (int kk = 0; kk < 16; ++kk) s += lsf[bb * 1024 + kk * 64 + l];
#pragma unroll
      for (int off = 32; off > 0; off >>= 1) s += __shfl_xor(s, off, 64);
      const float mean = s * (1.f / D_);
      float vv = 0.f;
#pragma unroll
      for (int kk = 0; kk < 16; ++kk) {
        float d = lsf[bb * 1024 + kk * 64 + l] - mean; vv += d * d;
      }
#pragma unroll
      for (int off = 32; off > 0; off >>= 1) vv += __shfl_xor(vv, off, 64);
      const float rs = rsqrtf(vv * (1.f / D_) + EPS_);
#pragma unroll
      for (int kk = 0; kk < 16; ++kk) {
        int idx = kk * 64 + l;
        lsf[bb * 1024 + idx] =
            (lsf[bb * 1024 + idx] - mean) * rs * p.g1[idx] + p.be1[idx];
      }
    }
    __syncthreads();
    const int r = wk * 4 + w;
    float acc[8] = {};
#pragma unroll
    for (int ch = 0; ch < 4; ++ch) {
      float4 wv = *(const float4*)(p.W1 + (size_t)r * D_ + ch * 256 + l * 4);
#pragma unroll
      for (int b = 0; b < 8; ++b) {
        const float* pp = &lsf[b * D_ + ch * 256 + l * 4];
        acc[b] += wv.x * pp[0] + wv.y * pp[1] + wv.z * pp[2] + wv.w * pp[3];
      }
    }
#pragma unroll
    for (int off = 32; off > 0; off >>= 1)
#pragma unroll
      for (int b = 0; b < 8; ++b) acc[b] += __shfl_down(acc[b], off, 64);
    if (l == 0) {
      const float bs = p.b1[r];
#pragma unroll
      for (int b = 0; b < 8; ++b)
        st_wt_u16((u16*)p.f1 + (size_t)b * FF_ + r, f2bfbits(fmaxf(acc[b] + bs, 0.f)));
    }
    __syncthreads();
  }
  gridbar(p.bar, 7);

  // ---- P8: f2 = W2 . f1 + b2 (bf16 in) ----
  for (int wk = bid; wk < 256; wk += G) {
    u16* lsb = (u16*)smem_;
#pragma unroll
    for (int i = 0; i < 8; ++i) {
      int flat = (t + i * 256) * 8;
      *(uint4*)&lsb[flat] = *(const uint4*)((const u16*)p.f1 + flat);
    }
    __syncthreads();
    const int w = t >> 6, l = t & 63;
    const int r = wk * 4 + w;
    float acc[8] = {};
#pragma unroll
    for (int ch = 0; ch < 8; ++ch) {
      float4 wv = *(const float4*)(p.W2 + (size_t)r * FF_ + ch * 256 + l * 4);
#pragma unroll
      for (int b = 0; b < 8; ++b) {
        uint2 u = *(const uint2*)&lsb[b * FF_ + ch * 256 + l * 4];
        float2 p0 = bfpair(u.x), p1 = bfpair(u.y);
        acc[b] += wv.x * p0.x + wv.y * p0.y + wv.z * p1.x + wv.w * p1.y;
      }
    }
#pragma unroll
    for (int off = 32; off > 0; off >>= 1)
#pragma unroll
      for (int b = 0; b < 8; ++b) acc[b] += __shfl_down(acc[b], off, 64);
    if (l == 0) {
      const float bs = p.b2[r];
#pragma unroll
      for (int b = 0; b < 8; ++b) st_wt_f32(&p.f2[(size_t)b * D_ + r], acc[b] + bs);
    }
    __syncthreads();
  }
  gridbar(p.bar, 8);

  // ---- P9: out = LN2(LN1(cls+att) + f2)  (h0 recomputed locally) ----
  for (int wk = bid; wk < 8; wk += G) {
    float* v = (float*)smem_;
    float* red = (float*)(smem_ + D_ * 4);
    for (int i = t; i < D_; i += 256) v[i] = p.cls[i] + p.att[wk * D_ + i];
    __syncthreads();
    float ls = 0.f;
    for (int i = t; i < D_; i += 256) ls += v[i];
    const float mean1 = blk_sum(ls, red) * (1.f / D_);
    float lv = 0.f;
    for (int i = t; i < D_; i += 256) { float dk = v[i] - mean1; lv += dk * dk; }
    const float var1 = blk_sum(lv, red) * (1.f / D_);
    const float rs1 = rsqrtf(var1 + EPS_);
    for (int i = t; i < D_; i += 256) {
      float h0v = (v[i] - mean1) * rs1 * p.g1[i] + p.be1[i];
      v[i] = h0v + p.f2[wk * D_ + i];
    }
    __syncthreads();
    float ls2 = 0.f;
    for (int i = t; i < D_; i += 256) ls2 += v[i];
    const float mean2 = blk_sum(ls2, red) * (1.f / D_);
    float lv2 = 0.f;
    for (int i = t; i < D_; i += 256) { float dk = v[i] - mean2; lv2 += dk * dk; }
    const float var2 = blk_sum(lv2, red) * (1.f / D_);
    const float rs2 = rsqrtf(var2 + EPS_);
    for (int i = t; i < D_; i += 256)
      p.out[wk * D_ + i] = (v[i] - mean2) * rs2 * p.g2[i] + p.be2[i];
    __syncthreads();
  }
}

// ===========================================================================
// FALLBACK: proven 13-kernel path (used only if co-residency can't be met).
// ===========================================================================
__device__ __forceinline__ float block_sum(float x, float* red) {
  const int t = threadIdx.x;
  __syncthreads();
  red[t] = x;
  __syncthreads();
  for (int s = 128; s > 0; s >>= 1) {
    if (t < s) red[t] += red[t + s];
    __syncthreads();
  }
  return red[0];
}

__device__ __forceinline__ float block_max(float x, float* red) {
  const int t = threadIdx.x;
  __syncthreads();
  red[t] = x;
  __syncthreads();
  for (int s = 128; s > 0; s >>= 1) {
    if (t < s) red[t] = fmaxf(red[t], red[t + s]);
    __syncthreads();
  }
  return red[0];
}

__global__ void __launch_bounds__(256) build_seq_kernel(
    const float* __restrict__ x, const float* __restrict__ y,
    const float* __restrict__ cls, const float* __restrict__ sep,
    const float* __restrict__ px, const float* __restrict__ py,
    const int* __restrict__ x_len, const int* __restrict__ y_len,
    bf16* __restrict__ seq) {
  const int m = blockIdx.x, t = threadIdx.x;
  const int b = m / S_;
  const int s = m - b * S_;
  if (b >= B_) return;
  const float* src = nullptr;
  const float* add = nullptr;
  const int lx = x_len[b], ly = y_len[b];
  if (s == 0) src = cls;
  else if (s <= lx) { src = x + ((size_t)b * 512 + (s - 1)) * D_; add = px; }
  else if (s == lx + 1) src = sep;
  else if (s <= lx + ly + 1) { src = y + ((size_t)b * 512 + (s - lx - 2)) * D_; add = py; }
  else if (s == lx + ly + 2) src = sep;
  if (!src) return;
  float4 sv = ((const float4*)src)[t];
  if (add) {
    float4 av = ((const float4*)add)[t];
    sv.x += av.x; sv.y += av.y; sv.z += av.z; sv.w += av.w;
  }
  uint2 o;
  o.x = f2bfbits(sv.x) | (f2bfbits(sv.y) << 16);
  o.y = f2bfbits(sv.z) | (f2bfbits(sv.w) << 16);
  ((uint2*)(seq + (size_t)m * D_))[t] = o;
}

__global__ void __launch_bounds__(256) qproj_kernel(
    const float* __restrict__ cls, const float* __restrict__ Wqkv,
    const float* __restrict__ bqkv, float* __restrict__ q0s) {
  __shared__ float cl[D_];
  const int t = threadIdx.x;
  *(float4*)&cl[t * 4] = ((const float4*)cls)[t];
  __syncthreads();
  const int w = t >> 6, l = t & 63;
  const int r = blockIdx.x * 4 + w;
  float acc = 0.f;
#pragma unroll
  for (int ch = 0; ch < 4; ++ch) {
    float4 wv = *(const float4*)(Wqkv + (size_t)r * D_ + ch * 256 + l * 4);
    const float* c4 = &cl[ch * 256 + l * 4];
    acc += wv.x * c4[0] + wv.y * c4[1] + wv.z * c4[2] + wv.w * c4[3];
  }
#pragma unroll
  for (int off = 32; off > 0; off >>= 1) acc += __shfl_down(acc, off, 64);
  if (l == 0) q0s[r] = (acc + bqkv[r]) * 0.125f;
}

__global__ void __launch_bounds__(256) rproj_kernel(
    const float* __restrict__ Wqkv, const float* __restrict__ q0s,
    u16* __restrict__ RT_hi, u16* __restrict__ RT_lo) {
  const int h = blockIdx.y, cc = blockIdx.x, t = threadIdx.x;
  __shared__ float qs[64];
  if (t < 64) qs[t] = q0s[h * 64 + t];
  __syncthreads();
  const int c = cc * 256 + t;
  const float* Wk = Wqkv + (size_t)(D_ + h * 64) * D_ + c;
  float acc = 0.f;
#pragma unroll 8
  for (int e = 0; e < 64; ++e) acc += Wk[(size_t)e * D_] * qs[e];
  const u32 hb = f2bfbits(acc);
  union { u32 u; float f; } hv; hv.u = hb << 16;
  RT_hi[h * D_ + c] = (u16)hb;
  RT_lo[h * D_ + c] = (u16)f2bfbits(acc - hv.f);
}

__global__ void __launch_bounds__(256) scores_kernel(
    const bf16* __restrict__ seq, const u16* __restrict__ RT_hi,
    const u16* __restrict__ RT_lo, const int* __restrict__ x_len,
    const int* __restrict__ y_len, float* __restrict__ S) {
  const int m0 = blockIdx.x * 64;
  bool valid = false;
#pragma unroll
  for (int b = 0; b < B_; ++b) {
    int rs = b * S_, re = rs + x_len[b] + y_len[b] + 3;
    if (m0 < re && m0 + 64 > rs) valid = true;
  }
  if (!valid) return;
  const int t = threadIdx.x;
  const int w = t >> 6, lane = t & 63, lane16 = lane & 15, quad = lane >> 4;
  const int row = m0 + w * 16 + lane16;
  const u16* arow = (const u16*)seq + (size_t)row * D_ + quad * 8;
  const u16* bh = RT_hi + lane16 * D_ + quad * 8;
  const u16* bl = RT_lo + lane16 * D_ + quad * 8;
  floatx4 acc = {};
#pragma unroll 4
  for (int kt = 0; kt < 32; ++kt) {
    bf16x8 a  = *(const bf16x8*)(arow + kt * 32);
    bf16x8 vh = *(const bf16x8*)(bh + kt * 32);
    bf16x8 vl = *(const bf16x8*)(bl + kt * 32);
    acc = __builtin_amdgcn_mfma_f32_16x16x32_bf16(a, vh, acc, 0, 0, 0);
    acc = __builtin_amdgcn_mfma_f32_16x16x32_bf16(a, vl, acc, 0, 0, 0);
  }
  *(floatx4*)&S[(size_t)lane16 * MPAD_ + m0 + w * 16 + quad * 4] = acc;
}

__global__ void __launch_bounds__(256) softmax_kernel(
    const float* __restrict__ S, const int* __restrict__ x_len,
    const int* __restrict__ y_len, u16* __restrict__ P) {
  const int h = blockIdx.x, b = blockIdx.y, t = threadIdx.x;
  const int n = x_len[b] + y_len[b] + 3;
  __shared__ float sc[PSTR_];
  __shared__ float red[256];
  const float* Sp = S + (size_t)h * MPAD_ + b * S_;
  float lmax = -3.0e38f;
  for (int k = t; k < n; k += 256) {
    float s = Sp[k];
    sc[k] = s;
    lmax = fmaxf(lmax, s);
  }
  const float gmax = block_max(lmax, red);
  float lsum = 0.f;
  for (int k = t; k < n; k += 256) {
    float p = __expf(sc[k] - gmax);
    sc[k] = p;
    lsum += p;
  }
  const float inv = 1.0f / block_sum(lsum, red);
  u16* Pp = P + (size_t)(h * 8 + b) * PSTR_;
  for (int k = t; k < PSTR_; k += 256)
    Pp[k] = (k < n) ? (u16)f2bfbits(sc[k] * inv) : (u16)0;
}

__global__ void __launch_bounds__(256) cbar_kernel(
    const bf16* __restrict__ seq, const u16* __restrict__ P,
    const int* __restrict__ x_len, const int* __restrict__ y_len,
    float* __restrict__ cbar) {
  const int ct = blockIdx.x, b = blockIdx.y, t = threadIdx.x;
  const int c0 = ct * 64;
  const int n = x_len[b] + y_len[b] + 3;
  const int nkt = (n + 31) >> 5;
  __shared__ u16 tile[32 * 68];
  const int w = t >> 6, lane = t & 63, lane16 = lane & 15, quad = lane >> 4;
  const int sk = t >> 3, scg = (t & 7) * 8;
  floatx4 acc = {};
  for (int kt = 0; kt < nkt; ++kt) {
    const int k0 = kt * 32;
    __syncthreads();
    uint4 v = make_uint4(0u, 0u, 0u, 0u);
    if (k0 + sk < n)
      v = *(const uint4*)((const u16*)seq + (size_t)(b * S_ + k0 + sk) * D_ + c0 + scg);
    *(uint2*)&tile[sk * 68 + scg]     = make_uint2(v.x, v.y);
    *(uint2*)&tile[sk * 68 + scg + 4] = make_uint2(v.z, v.w);
    __syncthreads();
    bf16x8 a = *(const bf16x8*)(P + (size_t)(lane16 * 8 + b) * PSTR_ + k0 + quad * 8);
    union { bf16x8 v; u16 u[8]; } bu;
#pragma unroll
    for (int j = 0; j < 8; ++j)
      bu.u[j] = tile[(quad * 8 + j) * 68 + w * 16 + lane16];
    acc = __builtin_amdgcn_mfma_f32_16x16x32_bf16(a, bu.v, acc, 0, 0, 0);
  }
#pragma unroll
  for (int r = 0; r < 4; ++r)
    cbar[(size_t)(b * 16 + quad * 4 + r) * D_ + c0 + w * 16 + lane16] = acc[r];
}

template <int K, int N, int BSTR, bool INBF, bool OUTBF, bool RELU, bool PERHEAD>
__global__ void __launch_bounds__(256) gemv8_kernel(
    const void* __restrict__ in_, const float* __restrict__ W,
    const float* __restrict__ bias, void* __restrict__ out_) {
  const int t = threadIdx.x;
  const int hoff = PERHEAD ? ((blockIdx.x * 4) >> 6) * D_ : 0;
  __shared__ u16 lsb[INBF ? 8 * K : 1];
  __shared__ float lsf[INBF ? 1 : 8 * K];
  if (INBF) {
    const u16* in = (const u16*)in_;
    const int per = 8 * K / (256 * 8);
#pragma unroll
    for (int i = 0; i < per; ++i) {
      int flat = (t + i * 256) * 8;
      int b = flat / K, k = flat % K;
      *(uint4*)&lsb[flat] = *(const uint4*)(in + (size_t)b * BSTR + hoff + k);
    }
  } else {
    const float* in = (const float*)in_;
    const int per = 8 * K / (256 * 4);
#pragma unroll
    for (int i = 0; i < per; ++i) {
      int flat = (t + i * 256) * 4;
      int b = flat / K, k = flat % K;
      *(float4*)&lsf[flat] = *(const float4*)(in + (size_t)b * BSTR + hoff + k);
    }
  }
  __syncthreads();
  const int w = t >> 6, l = t & 63;
  const int r = blockIdx.x * 4 + w;
  float acc[8] = {};
#pragma unroll
  for (int ch = 0; ch < K / 256; ++ch) {
    float4 wv = *(const float4*)(W + (size_t)r * K + ch * 256 + l * 4);
#pragma unroll
    for (int b = 0; b < 8; ++b) {
      float i0, i1, i2, i3;
      if (INBF) {
        uint2 u = *(const uint2*)&lsb[b * K + ch * 256 + l * 4];
        float2 p0 = bfpair(u.x), p1 = bfpair(u.y);
        i0 = p0.x; i1 = p0.y; i2 = p1.x; i3 = p1.y;
      } else {
        const float* p = &lsf[b * K + ch * 256 + l * 4];
        i0 = p[0]; i1 = p[1]; i2 = p[2]; i3 = p[3];
      }
      acc[b] += wv.x * i0 + wv.y * i1 + wv.z * i2 + wv.w * i3;
    }
  }
#pragma unroll
  for (int off = 32; off > 0; off >>= 1)
#pragma unroll
    for (int b = 0; b < 8; ++b) acc[b] += __shfl_down(acc[b], off, 64);
  if (l == 0) {
    const float bs = bias[r];
#pragma unroll
    for (int b = 0; b < 8; ++b) {
      float v = acc[b] + bs;
      if (RELU) v = fmaxf(v, 0.f);
      if (OUTBF) ((bf16*)out_)[(size_t)b * N + r] = __float2bfloat16(v);
      else       ((float*)out_)[(size_t)b * N + r] = v;
    }
  }
}

template <bool SECOND>
__global__ void __launch_bounds__(256) ln_kernel(
    const float* __restrict__ cls, const float* __restrict__ a,
    const float* __restrict__ bvec, const float* __restrict__ g,
    const float* __restrict__ be, float* __restrict__ out) {
  const int b = blockIdx.x, t = threadIdx.x;
  __shared__ float v[D_];
  __shared__ float red[256];
  for (int i = t; i < D_; i += 256) {
    float val;
    if (SECOND) val = a[b * D_ + i] + bvec[b * D_ + i];
    else        val = cls[i] + a[b * D_ + i];
    v[i] = val;
  }
  __syncthreads();
  float ls = 0.f;
  for (int i = t; i < D_; i += 256) ls += v[i];
  const float mean = block_sum(ls, red) * (1.f / D_);
  float lv = 0.f;
  for (int i = t; i < D_; i += 256) { float dk = v[i] - mean; lv += dk * dk; }
  const float var = block_sum(lv, red) * (1.f / D_);
  const float rs = rsqrtf(var + EPS_);
  for (int i = t; i < D_; i += 256)
    out[b * D_ + i] = (v[i] - mean) * rs * g[i] + be[i];
}

// ---------------------------------------------------------------------------
extern "C" void kernel_launch(void* const* d_in, const int* in_sizes, int n_in,
                              void* d_out, int out_size, void* d_ws, size_t ws_size,
                              hipStream_t stream) {
  (void)in_sizes; (void)n_in; (void)out_size; (void)ws_size;
  const float* x    = (const float*)d_in[0];
  const float* y    = (const float*)d_in[1];
  const float* cls  = (const float*)d_in[2];
  const float* sep  = (const float*)d_in[3];
  const float* px   = (const float*)d_in[4];
  const float* py   = (const float*)d_in[5];
  const float* Wqkv = (const float*)d_in[6];
  const float* bqkv = (const float*)d_in[7];
  const float* Wo   = (const float*)d_in[8];
  const float* bo   = (const float*)d_in[9];
  const float* W1   = (const float*)d_in[10];
  const float* b1   = (const float*)d_in[11];
  const float* W2   = (const float*)d_in[12];
  const float* b2   = (const float*)d_in[13];
  const float* g1   = (const float*)d_in[14];
  const float* be1  = (const float*)d_in[15];
  const float* g2   = (const float*)d_in[16];
  const float* be2  = (const float*)d_in[17];
  const int* xl     = (const int*)d_in[18];
  const int* yl     = (const int*)d_in[19];

  char* ws = (char*)d_ws;
  bf16*  seq   = (bf16*)(ws + OFF_SEQ);
  u16*   RT_hi = (u16*)(ws + OFF_RTHI);
  u16*   RT_lo = (u16*)(ws + OFF_RTLO);
  float* S     = (float*)(ws + OFF_S);
  u16*   P     = (u16*)(ws + OFF_P);
  float* cbar4 = (float*)(ws + OFF_CBAR);
  float* o0    = (float*)(ws + OFF_O0);
  float* att   = (float*)(ws + OFF_ATT);
  bf16*  f1    = (bf16*)(ws + OFF_F1);
  float* f2    = (float*)(ws + OFF_F2);
  u32*   bar   = (u32*)(ws + OFF_BAR);
  float* q0s   = (float*)(ws + OFF_Q0S);
  float* h0    = (float*)(ws + OFF_H0);

  KP kp;
  kp.x = x; kp.y = y; kp.cls = cls; kp.sep = sep; kp.px = px; kp.py = py;
  kp.Wqkv = Wqkv; kp.bqkv = bqkv; kp.Wo = Wo; kp.bo = bo;
  kp.W1 = W1; kp.b1 = b1; kp.W2 = W2; kp.b2 = b2;
  kp.g1 = g1; kp.be1 = be1; kp.g2 = g2; kp.be2 = be2;
  kp.xl = xl; kp.yl = yl;
  kp.seq = seq; kp.RT_hi = RT_hi; kp.RT_lo = RT_lo;
  kp.S = S; kp.P = P; kp.cbar4 = cbar4;
  kp.o0 = o0; kp.att = att; kp.f1 = f1; kp.f2 = f2;
  kp.out = (float*)d_out;
  kp.bar = bar;

  // Co-residency capacity check (cached). Plain launch; no cooperative API.
  static int mega_grid = -2;
  if (mega_grid == -2) {
    int nb = 0, ncu = 256;
    hipDeviceProp_t props;
    if (hipGetDeviceProperties(&props, 0) == hipSuccess)
      ncu = props.multiProcessorCount;
    if (hipOccupancyMaxActiveBlocksPerMultiprocessor(&nb, mega_kernel, 256, 0) ==
            hipSuccess && nb > 0) {
      long g = (long)nb * ncu;
      mega_grid = (int)(g < MAXGRID_ ? g : MAXGRID_);
    } else {
      mega_grid = -1;
    }
    if (mega_grid < 72) mega_grid = -1;  // P1 split needs >64 blocks
  }

  if (mega_grid > 0) {
    // zero barrier state (workspace is re-poisoned by the harness each iter)
    hipMemsetAsync(ws + OFF_BAR, 0, 4096, stream);
    mega_kernel<<<mega_grid, 256, 0, stream>>>(kp);
  } else {
    build_seq_kernel<<<MPAD_, 256, 0, stream>>>(x, y, cls, sep, px, py, xl, yl, seq);
    qproj_kernel<<<256, 256, 0, stream>>>(cls, Wqkv, bqkv, q0s);
    rproj_kernel<<<dim3(4, 16), 256, 0, stream>>>(Wqkv, q0s, RT_hi, RT_lo);
    scores_kernel<<<130, 256, 0, stream>>>(seq, RT_hi, RT_lo, xl, yl, S);
    softmax_kernel<<<dim3(16, 8), 256, 0, stream>>>(S, xl, yl, P);
    cbar_kernel<<<dim3(16, 8), 256, 0, stream>>>(seq, P, xl, yl, cbar4);
    gemv8_kernel<1024, 1024, 16384, false, false, false, true>
        <<<256, 256, 0, stream>>>(cbar4, Wqkv + (size_t)2048 * 1024, bqkv + 2048, o0);
    gemv8_kernel<1024, 1024, 1024, false, false, false, false>
        <<<256, 256, 0, stream>>>(o0, Wo, bo, att);
    ln_kernel<false><<<B_, 256, 0, stream>>>(cls, att, nullptr, g1, be1, h0);
    gemv8_kernel<1024, 2048, 1024, false, true, true, false>
        <<<512, 256, 0, stream>>>(h0, W1, b1, f1);
    gemv8_kernel<2048, 1024, 2048, true, false, false, false>
        <<<256, 256, 0, stream>>>(f1, W2, b2, f2);
    ln_kernel<true><<<B_, 256, 0, stream>>>(nullptr, h0, f2, g2, be2, (float*)d_out);
  }
}

// Round 7
// 201.740 us; speedup vs baseline: 1.1140x; 1.0146x over previous
//
#include <hip/hip_runtime.h>
#include <hip/hip_bf16.h>

#define D_ 1024
#define H_ 16
#define FF_ 2048
#define B_ 8
#define S_ 1027
#define BS_ 8216     /* B_*S_ */
#define MPAD_ 8320   /* 130 * 64 */
#define PSTR_ 1056   /* padded key stride for P */
#define EPS_ 1e-5f
#define MAXGRID_ 1024
#define NTILE_ 130
#define NBUCK_ 32
#define SPC_ 133120  /* S piece stride in floats = 16*MPAD_ */

/* workspace offsets */
#define OFF_SEQ  0
#define OFF_RTHI 17039360
#define OFF_RTLO 17072128
#define OFF_S    17104896   /* fallback single S */
#define OFF_P    17637376
#define OFF_CBAR 17907712   /* 4 pieces x 524288 */
#define OFF_O0   20004864
#define OFF_ATT  20037632
#define OFF_F1   20070400
#define OFF_F2   20103168
#define OFF_BAR  20135936
#define OFF_Q0S  20140032   /* fallback only */
#define OFF_H0   20144128   /* fallback only */
#define OFF_S4   20148224   /* mega: 4 pieces x 532480 */

typedef __hip_bfloat16 bf16;
typedef unsigned short u16;
typedef unsigned int u32;
typedef __attribute__((ext_vector_type(4))) float floatx4;
typedef __bf16 bf16x8 __attribute__((ext_vector_type(8)));

__device__ __forceinline__ float2 bfpair(u32 u) {
  union { u32 u; float f; } lo, hi;
  lo.u = u << 16; hi.u = u & 0xffff0000u;
  return make_float2(lo.f, hi.f);
}

__device__ __forceinline__ u32 f2bfbits(float f) {
  union { bf16 h; u16 u; } cv; cv.h = __float2bfloat16(f); return (u32)cv.u;
}

// ---------------------------------------------------------------------------
// Write-through stores (sc0 sc1): bypass the non-coherent per-XCD L2s so data
// is globally visible at the MALL once vmcnt retires. Used for ALL inter-phase
// intermediates; makes the grid barrier fence-free (proven R3: 460->95us).
// ---------------------------------------------------------------------------
__device__ __forceinline__ void st_wt_f32(float* p, float v) {
  asm volatile("global_store_dword %0, %1, off sc0 sc1" :: "v"(p), "v"(v) : "memory");
}
__device__ __forceinline__ void st_wt_u16(u16* p, u32 v) {
  asm volatile("global_store_short %0, %1, off sc0 sc1" :: "v"(p), "v"(v) : "memory");
}
__device__ __forceinline__ void st_wt_v2(void* p, uint2 v) {
  asm volatile("global_store_dwordx2 %0, %1, off sc0 sc1" :: "v"(p), "v"(v) : "memory");
}
__device__ __forceinline__ void st_wt_f4(void* p, floatx4 v) {
  asm volatile("global_store_dwordx4 %0, %1, off sc0 sc1" :: "v"(p), "v"(v) : "memory");
}

// Fast block reductions: wave shuffle + 4-slot LDS combine.
__device__ __forceinline__ float blk_sum(float x, float* red) {
#pragma unroll
  for (int off = 32; off > 0; off >>= 1) x += __shfl_down(x, off, 64);
  __syncthreads();
  if ((threadIdx.x & 63) == 0) red[threadIdx.x >> 6] = x;
  __syncthreads();
  return red[0] + red[1] + red[2] + red[3];
}

__device__ __forceinline__ float blk_max(float x, float* red) {
#pragma unroll
  for (int off = 32; off > 0; off >>= 1) x = fmaxf(x, __shfl_down(x, off, 64));
  __syncthreads();
  if ((threadIdx.x & 63) == 0) red[threadIdx.x >> 6] = x;
  __syncthreads();
  return fmaxf(fmaxf(red[0], red[1]), fmaxf(red[2], red[3]));
}

// ---------------------------------------------------------------------------
// Fence-free grid barrier, GEN-BROADCAST form (R4/R6-proven). 511+ blocks
// poll ONE gen line; only block0 sweeps the 32 arrival buckets. R5's all-poll
// variant regressed (polling storm). '==' safe: phase k+1 arrivals only start
// after gen=k is published.
// ---------------------------------------------------------------------------
__device__ __forceinline__ void gridbar(u32* bar, u32 phase) {
  asm volatile("s_waitcnt vmcnt(0) lgkmcnt(0)" ::: "memory");
  __syncthreads();
  if (threadIdx.x == 0) {
    __hip_atomic_fetch_add(bar + (blockIdx.x & (NBUCK_ - 1)) * 16, 1u,
                           __ATOMIC_RELAXED, __HIP_MEMORY_SCOPE_AGENT);
    u32* gen = bar + NBUCK_ * 16;
    if (blockIdx.x == 0) {
      const u32 target = (u32)gridDim.x * phase;
      int spins = 0;
      for (;;) {
        u32 s = 0;
#pragma unroll
        for (int i = 0; i < NBUCK_; ++i)
          s += __hip_atomic_load(bar + i * 16, __ATOMIC_RELAXED,
                                 __HIP_MEMORY_SCOPE_AGENT);
        if (s == target) break;
        __builtin_amdgcn_s_sleep(1);
        if (++spins > 300000) break;  // safety: never hang the queue
      }
      __hip_atomic_store(gen, phase, __ATOMIC_RELAXED, __HIP_MEMORY_SCOPE_AGENT);
    } else {
      int spins = 0;
      while (__hip_atomic_load(gen, __ATOMIC_RELAXED,
                               __HIP_MEMORY_SCOPE_AGENT) < phase) {
        __builtin_amdgcn_s_sleep(2);
        if (++spins > 300000) break;  // safety
      }
    }
  }
  __syncthreads();
}

struct KP {
  const float *x, *y, *cls, *sep, *px, *py;
  const float *Wqkv, *bqkv, *Wo, *bo, *W1, *b1, *W2, *b2;
  const float *g1, *be1, *g2, *be2;
  const int *xl, *yl;
  bf16* seq; u16* RT_hi; u16* RT_lo; float* S4; u16* P;
  float* cbar4; float* o0; float* att; bf16* f1; float* f2; float* out;
  u32* bar;
};

__device__ __forceinline__ const float* row_src(const KP& p, int m,
                                                const int* lx8, const int* ly8,
                                                const float** add) {
  const int b = m / S_;
  const int s = m - b * S_;
  const int lx = lx8[b], ly = ly8[b];
  *add = nullptr;
  if (s == 0) return p.cls;
  if (s <= lx) { *add = p.px; return p.x + ((size_t)b * 512 + (s - 1)) * D_; }
  if (s == lx + 1) return p.sep;
  if (s <= lx + ly + 1) { *add = p.py; return p.y + ((size_t)b * 512 + (s - lx - 2)) * D_; }
  if (s == lx + ly + 2) return p.sep;
  return nullptr;
}

// ===========================================================================
// MEGA KERNEL v7 = v6 (84us proven) + grid up to 1024 (4 blk/CU by LDS) +
// P2 scores split into 4 K-quarters (520 units, 4x shorter serial chain),
// summed deterministically in P3.
// ===========================================================================
__global__ void __launch_bounds__(256, 2) mega_kernel(KP p) {
  __shared__ __align__(16) char smem_[33792];
  const int t = threadIdx.x;
  const int bid = blockIdx.x;
  const int G = gridDim.x;

  // Entry: per-block acquire fence drops stale (poisoned) cache lines before
  // this block's first workspace read. Producers store write-through, so no
  // cross-block ordering is needed for the invalidate -> no grid barrier.
  if (t == 0) __builtin_amdgcn_fence(__ATOMIC_ACQUIRE, "agent");
  __syncthreads();

  // ---- P1: rproj (inline qproj) on blocks 0..63 || build_seq (2-deep) ----
  if (bid < 64) {
    const int h = bid >> 2, cc = bid & 3;
    float* cl = (float*)smem_;
    float* qs = (float*)(smem_ + 4096);
    *(float4*)&cl[t * 4] = ((const float4*)p.cls)[t];
    __syncthreads();
    const int r = t >> 2, j = t & 3;
    const float* wr = p.Wqkv + (size_t)(h * 64 + r) * D_;
    float acc = 0.f;
#pragma unroll 8
    for (int i = 0; i < 64; ++i) {
      float4 wv = *(const float4*)(wr + i * 16 + j * 4);
      const float* c4 = &cl[i * 16 + j * 4];
      acc += wv.x * c4[0] + wv.y * c4[1] + wv.z * c4[2] + wv.w * c4[3];
    }
    acc += __shfl_xor(acc, 1, 64);
    acc += __shfl_xor(acc, 2, 64);
    if (j == 0) qs[r] = (acc + p.bqkv[h * 64 + r]) * 0.125f;
    __syncthreads();
    const int c = cc * 256 + t;
    const float* Wk = p.Wqkv + (size_t)(D_ + h * 64) * D_ + c;
    float a2 = 0.f;
#pragma unroll 8
    for (int e = 0; e < 64; ++e) a2 += Wk[(size_t)e * D_] * qs[e];
    const u32 hb = f2bfbits(a2);
    union { u32 u; float f; } hv; hv.u = hb << 16;
    st_wt_u16(p.RT_hi + h * D_ + c, hb);
    st_wt_u16(p.RT_lo + h * D_ + c, f2bfbits(a2 - hv.f));
  } else {
    int lx8[8], ly8[8];
#pragma unroll
    for (int b = 0; b < 8; ++b) { lx8[b] = p.xl[b]; ly8[b] = p.yl[b]; }
    const int stride = G - 64;
    for (int m0 = bid - 64; m0 < BS_; m0 += 2 * stride) {
      const int m1 = m0 + stride;
      const float *ad0, *ad1 = nullptr;
      const float* s0 = row_src(p, m0, lx8, ly8, &ad0);
      const float* s1 = (m1 < BS_) ? row_src(p, m1, lx8, ly8, &ad1) : nullptr;
      float4 v0, a0v, v1, a1v;
      if (s0) v0 = ((const float4*)s0)[t];
      if (ad0) a0v = ((const float4*)ad0)[t];
      if (s1) v1 = ((const float4*)s1)[t];
      if (ad1) a1v = ((const float4*)ad1)[t];
      if (s0) {
        if (ad0) { v0.x += a0v.x; v0.y += a0v.y; v0.z += a0v.z; v0.w += a0v.w; }
        uint2 o;
        o.x = f2bfbits(v0.x) | (f2bfbits(v0.y) << 16);
        o.y = f2bfbits(v0.z) | (f2bfbits(v0.w) << 16);
        st_wt_v2((u16*)p.seq + (size_t)m0 * D_ + t * 4, o);
      }
      if (s1) {
        if (ad1) { v1.x += a1v.x; v1.y += a1v.y; v1.z += a1v.z; v1.w += a1v.w; }
        uint2 o;
        o.x = f2bfbits(v1.x) | (f2bfbits(v1.y) << 16);
        o.y = f2bfbits(v1.z) | (f2bfbits(v1.w) << 16);
        st_wt_v2((u16*)p.seq + (size_t)m1 * D_ + t * 4, o);
      }
    }
  }
  gridbar(p.bar, 1);

  // ---- P2: scores, K split into 4 quarters (520 units, 8 kt each) ----
  for (int wk = bid; wk < 4 * NTILE_; wk += G) {
    const int piece = wk / NTILE_;
    const int tile = wk - piece * NTILE_;
    const int m0 = tile * 64;
    bool valid = false;
#pragma unroll
    for (int b = 0; b < B_; ++b) {
      int rs = b * S_, re = rs + p.xl[b] + p.yl[b] + 3;
      if (m0 < re && m0 + 64 > rs) valid = true;
    }
    if (!valid) continue;
    const int w = t >> 6, lane = t & 63, lane16 = lane & 15, quad = lane >> 4;
    const int row = m0 + w * 16 + lane16;
    const u16* arow = (const u16*)p.seq + (size_t)row * D_ + quad * 8;
    const u16* bh = p.RT_hi + lane16 * D_ + quad * 8;
    const u16* bl = p.RT_lo + lane16 * D_ + quad * 8;
    floatx4 acc = {};
    const int kt0 = piece * 8;
#pragma unroll
    for (int k = 0; k < 8; ++k) {
      const int kt = kt0 + k;
      bf16x8 a  = *(const bf16x8*)(arow + kt * 32);
      bf16x8 vh = *(const bf16x8*)(bh + kt * 32);
      bf16x8 vl = *(const bf16x8*)(bl + kt * 32);
      acc = __builtin_amdgcn_mfma_f32_16x16x32_bf16(a, vh, acc, 0, 0, 0);
      acc = __builtin_amdgcn_mfma_f32_16x16x32_bf16(a, vl, acc, 0, 0, 0);
    }
    st_wt_f4(&p.S4[(size_t)piece * SPC_ + (size_t)lane16 * MPAD_ + m0 + w * 16 + quad * 4], acc);
  }
  gridbar(p.bar, 2);

  // ---- P3: softmax per (h,b) over sum of 4 S pieces -> P (bf16) ----
  for (int wk = bid; wk < 128; wk += G) {
    const int h = wk >> 3, b = wk & 7;
    const int n = p.xl[b] + p.yl[b] + 3;
    float* sc = (float*)smem_;
    float* red = (float*)(smem_ + PSTR_ * 4);
    const float* Sp = p.S4 + (size_t)h * MPAD_ + b * S_;
    float lmax = -3.0e38f;
    for (int k = t; k < n; k += 256) {
      float s = Sp[k] + Sp[SPC_ + k] + Sp[2 * SPC_ + k] + Sp[3 * SPC_ + k];
      sc[k] = s;
      lmax = fmaxf(lmax, s);
    }
    const float gmax = blk_max(lmax, red);
    float lsum = 0.f;
    for (int k = t; k < n; k += 256) {
      float pr = __expf(sc[k] - gmax);
      sc[k] = pr;
      lsum += pr;
    }
    const float inv = 1.0f / blk_sum(lsum, red);
    u16* Pp = p.P + (size_t)(h * 8 + b) * PSTR_;
    for (int k = t; k < PSTR_; k += 256)
      st_wt_u16(Pp + k, (k < n) ? f2bfbits(sc[k] * inv) : 0u);
    __syncthreads();
  }
  gridbar(p.bar, 3);

  // ---- P4: cbar = P . seq via MFMA; K split 4-way into 4 buffers ----
  for (int wk = bid; wk < 512; wk += G) {
    const int ct = wk & 15, b = (wk >> 4) & 7, piece = wk >> 7;
    const int c0 = ct * 64;
    const int n = p.xl[b] + p.yl[b] + 3;
    const int nkt = (n + 31) >> 5;
    const int KR0[4] = {0, 9, 17, 25};
    const int KR1[4] = {9, 17, 25, 33};
    const int kt0 = KR0[piece];
    const int kt1 = nkt < KR1[piece] ? nkt : KR1[piece];
    u16* tile = (u16*)smem_;  // [2][32*68]
    const int w = t >> 6, lane = t & 63, lane16 = lane & 15, quad = lane >> 4;
    const int sk = t >> 3, scg = (t & 7) * 8;
    floatx4 acc = {};
    uint4 v = make_uint4(0u, 0u, 0u, 0u);
    if (kt0 < kt1 && kt0 * 32 + sk < n)
      v = *(const uint4*)((const u16*)p.seq + (size_t)((size_t)b * S_ + kt0 * 32 + sk) * D_ + c0 + scg);
    for (int kt = kt0; kt < kt1; ++kt) {
      u16* tb = tile + (kt & 1) * (32 * 68);
      *(uint2*)&tb[sk * 68 + scg]     = make_uint2(v.x, v.y);
      *(uint2*)&tb[sk * 68 + scg + 4] = make_uint2(v.z, v.w);
      v = make_uint4(0u, 0u, 0u, 0u);
      if (kt + 1 < kt1 && (kt + 1) * 32 + sk < n)
        v = *(const uint4*)((const u16*)p.seq + (size_t)((size_t)b * S_ + (kt + 1) * 32 + sk) * D_ + c0 + scg);
      __syncthreads();
      bf16x8 a = *(const bf16x8*)(p.P + (size_t)(lane16 * 8 + b) * PSTR_ + kt * 32 + quad * 8);
      union { bf16x8 v8; u16 u[8]; } bu;
#pragma unroll
      for (int j = 0; j < 8; ++j)
        bu.u[j] = tb[(quad * 8 + j) * 68 + w * 16 + lane16];
      acc = __builtin_amdgcn_mfma_f32_16x16x32_bf16(a, bu.v8, acc, 0, 0, 0);
    }
    float* dst = p.cbar4 + (size_t)piece * 131072;
#pragma unroll
    for (int r = 0; r < 4; ++r)
      st_wt_f32(&dst[(size_t)(b * 16 + quad * 4 + r) * D_ + c0 + w * 16 + lane16], acc[r]);
    __syncthreads();
  }
  gridbar(p.bar, 4);

  // ---- P5: o0 = Wv . (sum of 4 cbar pieces) + bv (per-head input slice) ----
  for (int wk = bid; wk < 256; wk += G) {
    float* lsf = (float*)smem_;
    const int hoff = ((wk * 4) >> 6) * D_;
#pragma unroll
    for (int i = 0; i < 8; ++i) {
      int flat = (t + i * 256) * 4;
      int b = flat >> 10, k = flat & 1023;
      size_t off = (size_t)b * 16384 + hoff + k;
      float4 a0 = *(const float4*)(p.cbar4 + off);
      float4 a1 = *(const float4*)(p.cbar4 + 131072 + off);
      float4 a2 = *(const float4*)(p.cbar4 + 262144 + off);
      float4 a3 = *(const float4*)(p.cbar4 + 393216 + off);
      a0.x += a1.x + a2.x + a3.x; a0.y += a1.y + a2.y + a3.y;
      a0.z += a1.z + a2.z + a3.z; a0.w += a1.w + a2.w + a3.w;
      *(float4*)&lsf[flat] = a0;
    }
    __syncthreads();
    const int w = t >> 6, l = t & 63;
    const int r = wk * 4 + w;
    const float* W = p.Wqkv + (size_t)2048 * 1024;
    float acc[8] = {};
#pragma unroll
    for (int ch = 0; ch < 4; ++ch) {
      float4 wv = *(const float4*)(W + (size_t)r * D_ + ch * 256 + l * 4);
#pragma unroll
      for (int b = 0; b < 8; ++b) {
        const float* pp = &lsf[b * D_ + ch * 256 + l * 4];
        acc[b] += wv.x * pp[0] + wv.y * pp[1] + wv.z * pp[2] + wv.w * pp[3];
      }
    }
#pragma unroll
    for (int off = 32; off > 0; off >>= 1)
#pragma unroll
      for (int b = 0; b < 8; ++b) acc[b] += __shfl_down(acc[b], off, 64);
    if (l == 0) {
      const float bs = p.bqkv[2048 + r];
#pragma unroll
      for (int b = 0; b < 8; ++b) st_wt_f32(&p.o0[(size_t)b * D_ + r], acc[b] + bs);
    }
    __syncthreads();
  }
  gridbar(p.bar, 5);

  // ---- P6: att = Wo . o0 + bo ----
  for (int wk = bid; wk < 256; wk += G) {
    float* lsf = (float*)smem_;
#pragma unroll
    for (int i = 0; i < 8; ++i) {
      int flat = (t + i * 256) * 4;
      *(float4*)&lsf[flat] = *(const float4*)(p.o0 + flat);
    }
    __syncthreads();
    const int w = t >> 6, l = t & 63;
    const int r = wk * 4 + w;
    float acc[8] = {};
#pragma unroll
    for (int ch = 0; ch < 4; ++ch) {
      float4 wv = *(const float4*)(p.Wo + (size_t)r * D_ + ch * 256 + l * 4);
#pragma unroll
      for (int b = 0; b < 8; ++b) {
        const float* pp = &lsf[b * D_ + ch * 256 + l * 4];
        acc[b] += wv.x * pp[0] + wv.y * pp[1] + wv.z * pp[2] + wv.w * pp[3];
      }
    }
#pragma unroll
    for (int off = 32; off > 0; off >>= 1)
#pragma unroll
      for (int b = 0; b < 8; ++b) acc[b] += __shfl_down(acc[b], off, 64);
    if (l == 0) {
      const float bs = p.bo[r];
#pragma unroll
      for (int b = 0; b < 8; ++b) st_wt_f32(&p.att[(size_t)b * D_ + r], acc[b] + bs);
    }
    __syncthreads();
  }
  gridbar(p.bar, 6);

  // ---- P7: f1 = relu(W1 . LN1(cls+att) + b1); LN1 computed in-block ----
  for (int wk = bid; wk < 512; wk += G) {
    float* lsf = (float*)smem_;
#pragma unroll
    for (int i = 0; i < 8; ++i) {
      int flat = (t + i * 256) * 4;
      int b = flat >> 10, k = flat & 1023;
      float4 av = *(const float4*)(p.att + (size_t)b * D_ + k);
      float4 cv = *(const float4*)(p.cls + k);
      av.x += cv.x; av.y += cv.y; av.z += cv.z; av.w += cv.w;
      *(float4*)&lsf[flat] = av;
    }
    __syncthreads();
    const int w = t >> 6, l = t & 63;
#pragma unroll
    for (int bb = 2 * w; bb < 2 * w + 2; ++bb) {
      float s = 0.f;
#pragma unroll
      for (int kk = 0; kk < 16; ++kk) s += lsf[bb * 1024 + kk * 64 + l];
#pragma unroll
      for (int off = 32; off > 0; off >>= 1) s += __shfl_xor(s, off, 64);
      const float mean = s * (1.f / D_);
      float vv = 0.f;
#pragma unroll
      for (int kk = 0; kk < 16; ++kk) {
        float d = lsf[bb * 1024 + kk * 64 + l] - mean; vv += d * d;
      }
#pragma unroll
      for (int off = 32; off > 0; off >>= 1) vv += __shfl_xor(vv, off, 64);
      const float rs = rsqrtf(vv * (1.f / D_) + EPS_);
#pragma unroll
      for (int kk = 0; kk < 16; ++kk) {
        int idx = kk * 64 + l;
        lsf[bb * 1024 + idx] =
            (lsf[bb * 1024 + idx] - mean) * rs * p.g1[idx] + p.be1[idx];
      }
    }
    __syncthreads();
    const int r = wk * 4 + w;
    float acc[8] = {};
#pragma unroll
    for (int ch = 0; ch < 4; ++ch) {
      float4 wv = *(const float4*)(p.W1 + (size_t)r * D_ + ch * 256 + l * 4);
#pragma unroll
      for (int b = 0; b < 8; ++b) {
        const float* pp = &lsf[b * D_ + ch * 256 + l * 4];
        acc[b] += wv.x * pp[0] + wv.y * pp[1] + wv.z * pp[2] + wv.w * pp[3];
      }
    }
#pragma unroll
    for (int off = 32; off > 0; off >>= 1)
#pragma unroll
      for (int b = 0; b < 8; ++b) acc[b] += __shfl_down(acc[b], off, 64);
    if (l == 0) {
      const float bs = p.b1[r];
#pragma unroll
      for (int b = 0; b < 8; ++b)
        st_wt_u16((u16*)p.f1 + (size_t)b * FF_ + r, f2bfbits(fmaxf(acc[b] + bs, 0.f)));
    }
    __syncthreads();
  }
  gridbar(p.bar, 7);

  // ---- P8: f2 = W2 . f1 + b2 (bf16 in) ----
  for (int wk = bid; wk < 256; wk += G) {
    u16* lsb = (u16*)smem_;
#pragma unroll
    for (int i = 0; i < 8; ++i) {
      int flat = (t + i * 256) * 8;
      *(uint4*)&lsb[flat] = *(const uint4*)((const u16*)p.f1 + flat);
    }
    __syncthreads();
    const int w = t >> 6, l = t & 63;
    const int r = wk * 4 + w;
    float acc[8] = {};
#pragma unroll
    for (int ch = 0; ch < 8; ++ch) {
      float4 wv = *(const float4*)(p.W2 + (size_t)r * FF_ + ch * 256 + l * 4);
#pragma unroll
      for (int b = 0; b < 8; ++b) {
        uint2 u = *(const uint2*)&lsb[b * FF_ + ch * 256 + l * 4];
        float2 p0 = bfpair(u.x), p1 = bfpair(u.y);
        acc[b] += wv.x * p0.x + wv.y * p0.y + wv.z * p1.x + wv.w * p1.y;
      }
    }
#pragma unroll
    for (int off = 32; off > 0; off >>= 1)
#pragma unroll
      for (int b = 0; b < 8; ++b) acc[b] += __shfl_down(acc[b], off, 64);
    if (l == 0) {
      const float bs = p.b2[r];
#pragma unroll
      for (int b = 0; b < 8; ++b) st_wt_f32(&p.f2[(size_t)b * D_ + r], acc[b] + bs);
    }
    __syncthreads();
  }
  gridbar(p.bar, 8);

  // ---- P9: out = LN2(LN1(cls+att) + f2)  (h0 recomputed locally) ----
  for (int wk = bid; wk < 8; wk += G) {
    float* v = (float*)smem_;
    float* red = (float*)(smem_ + D_ * 4);
    for (int i = t; i < D_; i += 256) v[i] = p.cls[i] + p.att[wk * D_ + i];
    __syncthreads();
    float ls = 0.f;
    for (int i = t; i < D_; i += 256) ls += v[i];
    const float mean1 = blk_sum(ls, red) * (1.f / D_);
    float lv = 0.f;
    for (int i = t; i < D_; i += 256) { float dk = v[i] - mean1; lv += dk * dk; }
    const float var1 = blk_sum(lv, red) * (1.f / D_);
    const float rs1 = rsqrtf(var1 + EPS_);
    for (int i = t; i < D_; i += 256) {
      float h0v = (v[i] - mean1) * rs1 * p.g1[i] + p.be1[i];
      v[i] = h0v + p.f2[wk * D_ + i];
    }
    __syncthreads();
    float ls2 = 0.f;
    for (int i = t; i < D_; i += 256) ls2 += v[i];
    const float mean2 = blk_sum(ls2, red) * (1.f / D_);
    float lv2 = 0.f;
    for (int i = t; i < D_; i += 256) { float dk = v[i] - mean2; lv2 += dk * dk; }
    const float var2 = blk_sum(lv2, red) * (1.f / D_);
    const float rs2 = rsqrtf(var2 + EPS_);
    for (int i = t; i < D_; i += 256)
      p.out[wk * D_ + i] = (v[i] - mean2) * rs2 * p.g2[i] + p.be2[i];
    __syncthreads();
  }
}

// ===========================================================================
// FALLBACK: proven 13-kernel path (used only if co-residency can't be met).
// ===========================================================================
__device__ __forceinline__ float block_sum(float x, float* red) {
  const int t = threadIdx.x;
  __syncthreads();
  red[t] = x;
  __syncthreads();
  for (int s = 128; s > 0; s >>= 1) {
    if (t < s) red[t] += red[t + s];
    __syncthreads();
  }
  return red[0];
}

__device__ __forceinline__ float block_max(float x, float* red) {
  const int t = threadIdx.x;
  __syncthreads();
  red[t] = x;
  __syncthreads();
  for (int s = 128; s > 0; s >>= 1) {
    if (t < s) red[t] = fmaxf(red[t], red[t + s]);
    __syncthreads();
  }
  return red[0];
}

__global__ void __launch_bounds__(256) build_seq_kernel(
    const float* __restrict__ x, const float* __restrict__ y,
    const float* __restrict__ cls, const float* __restrict__ sep,
    const float* __restrict__ px, const float* __restrict__ py,
    const int* __restrict__ x_len, const int* __restrict__ y_len,
    bf16* __restrict__ seq) {
  const int m = blockIdx.x, t = threadIdx.x;
  const int b = m / S_;
  const int s = m - b * S_;
  if (b >= B_) return;
  const float* src = nullptr;
  const float* add = nullptr;
  const int lx = x_len[b], ly = y_len[b];
  if (s == 0) src = cls;
  else if (s <= lx) { src = x + ((size_t)b * 512 + (s - 1)) * D_; add = px; }
  else if (s == lx + 1) src = sep;
  else if (s <= lx + ly + 1) { src = y + ((size_t)b * 512 + (s - lx - 2)) * D_; add = py; }
  else if (s == lx + ly + 2) src = sep;
  if (!src) return;
  float4 sv = ((const float4*)src)[t];
  if (add) {
    float4 av = ((const float4*)add)[t];
    sv.x += av.x; sv.y += av.y; sv.z += av.z; sv.w += av.w;
  }
  uint2 o;
  o.x = f2bfbits(sv.x) | (f2bfbits(sv.y) << 16);
  o.y = f2bfbits(sv.z) | (f2bfbits(sv.w) << 16);
  ((uint2*)(seq + (size_t)m * D_))[t] = o;
}

__global__ void __launch_bounds__(256) qproj_kernel(
    const float* __restrict__ cls, const float* __restrict__ Wqkv,
    const float* __restrict__ bqkv, float* __restrict__ q0s) {
  __shared__ float cl[D_];
  const int t = threadIdx.x;
  *(float4*)&cl[t * 4] = ((const float4*)cls)[t];
  __syncthreads();
  const int w = t >> 6, l = t & 63;
  const int r = blockIdx.x * 4 + w;
  float acc = 0.f;
#pragma unroll
  for (int ch = 0; ch < 4; ++ch) {
    float4 wv = *(const float4*)(Wqkv + (size_t)r * D_ + ch * 256 + l * 4);
    const float* c4 = &cl[ch * 256 + l * 4];
    acc += wv.x * c4[0] + wv.y * c4[1] + wv.z * c4[2] + wv.w * c4[3];
  }
#pragma unroll
  for (int off = 32; off > 0; off >>= 1) acc += __shfl_down(acc, off, 64);
  if (l == 0) q0s[r] = (acc + bqkv[r]) * 0.125f;
}

__global__ void __launch_bounds__(256) rproj_kernel(
    const float* __restrict__ Wqkv, const float* __restrict__ q0s,
    u16* __restrict__ RT_hi, u16* __restrict__ RT_lo) {
  const int h = blockIdx.y, cc = blockIdx.x, t = threadIdx.x;
  __shared__ float qs[64];
  if (t < 64) qs[t] = q0s[h * 64 + t];
  __syncthreads();
  const int c = cc * 256 + t;
  const float* Wk = Wqkv + (size_t)(D_ + h * 64) * D_ + c;
  float acc = 0.f;
#pragma unroll 8
  for (int e = 0; e < 64; ++e) acc += Wk[(size_t)e * D_] * qs[e];
  const u32 hb = f2bfbits(acc);
  union { u32 u; float f; } hv; hv.u = hb << 16;
  RT_hi[h * D_ + c] = (u16)hb;
  RT_lo[h * D_ + c] = (u16)f2bfbits(acc - hv.f);
}

__global__ void __launch_bounds__(256) scores_kernel(
    const bf16* __restrict__ seq, const u16* __restrict__ RT_hi,
    const u16* __restrict__ RT_lo, const int* __restrict__ x_len,
    const int* __restrict__ y_len, float* __restrict__ S) {
  const int m0 = blockIdx.x * 64;
  bool valid = false;
#pragma unroll
  for (int b = 0; b < B_; ++b) {
    int rs = b * S_, re = rs + x_len[b] + y_len[b] + 3;
    if (m0 < re && m0 + 64 > rs) valid = true;
  }
  if (!valid) return;
  const int t = threadIdx.x;
  const int w = t >> 6, lane = t & 63, lane16 = lane & 15, quad = lane >> 4;
  const int row = m0 + w * 16 + lane16;
  const u16* arow = (const u16*)seq + (size_t)row * D_ + quad * 8;
  const u16* bh = RT_hi + lane16 * D_ + quad * 8;
  const u16* bl = RT_lo + lane16 * D_ + quad * 8;
  floatx4 acc = {};
#pragma unroll 4
  for (int kt = 0; kt < 32; ++kt) {
    bf16x8 a  = *(const bf16x8*)(arow + kt * 32);
    bf16x8 vh = *(const bf16x8*)(bh + kt * 32);
    bf16x8 vl = *(const bf16x8*)(bl + kt * 32);
    acc = __builtin_amdgcn_mfma_f32_16x16x32_bf16(a, vh, acc, 0, 0, 0);
    acc = __builtin_amdgcn_mfma_f32_16x16x32_bf16(a, vl, acc, 0, 0, 0);
  }
  *(floatx4*)&S[(size_t)lane16 * MPAD_ + m0 + w * 16 + quad * 4] = acc;
}

__global__ void __launch_bounds__(256) softmax_kernel(
    const float* __restrict__ S, const int* __restrict__ x_len,
    const int* __restrict__ y_len, u16* __restrict__ P) {
  const int h = blockIdx.x, b = blockIdx.y, t = threadIdx.x;
  const int n = x_len[b] + y_len[b] + 3;
  __shared__ float sc[PSTR_];
  __shared__ float red[256];
  const float* Sp = S + (size_t)h * MPAD_ + b * S_;
  float lmax = -3.0e38f;
  for (int k = t; k < n; k += 256) {
    float s = Sp[k];
    sc[k] = s;
    lmax = fmaxf(lmax, s);
  }
  const float gmax = block_max(lmax, red);
  float lsum = 0.f;
  for (int k = t; k < n; k += 256) {
    float p = __expf(sc[k] - gmax);
    sc[k] = p;
    lsum += p;
  }
  const float inv = 1.0f / block_sum(lsum, red);
  u16* Pp = P + (size_t)(h * 8 + b) * PSTR_;
  for (int k = t; k < PSTR_; k += 256)
    Pp[k] = (k < n) ? (u16)f2bfbits(sc[k] * inv) : (u16)0;
}

__global__ void __launch_bounds__(256) cbar_kernel(
    const bf16* __restrict__ seq, const u16* __restrict__ P,
    const int* __restrict__ x_len, const int* __restrict__ y_len,
    float* __restrict__ cbar) {
  const int ct = blockIdx.x, b = blockIdx.y, t = threadIdx.x;
  const int c0 = ct * 64;
  const int n = x_len[b] + y_len[b] + 3;
  const int nkt = (n + 31) >> 5;
  __shared__ u16 tile[32 * 68];
  const int w = t >> 6, lane = t & 63, lane16 = lane & 15, quad = lane >> 4;
  const int sk = t >> 3, scg = (t & 7) * 8;
  floatx4 acc = {};
  for (int kt = 0; kt < nkt; ++kt) {
    const int k0 = kt * 32;
    __syncthreads();
    uint4 v = make_uint4(0u, 0u, 0u, 0u);
    if (k0 + sk < n)
      v = *(const uint4*)((const u16*)seq + (size_t)(b * S_ + k0 + sk) * D_ + c0 + scg);
    *(uint2*)&tile[sk * 68 + scg]     = make_uint2(v.x, v.y);
    *(uint2*)&tile[sk * 68 + scg + 4] = make_uint2(v.z, v.w);
    __syncthreads();
    bf16x8 a = *(const bf16x8*)(P + (size_t)(lane16 * 8 + b) * PSTR_ + k0 + quad * 8);
    union { bf16x8 v; u16 u[8]; } bu;
#pragma unroll
    for (int j = 0; j < 8; ++j)
      bu.u[j] = tile[(quad * 8 + j) * 68 + w * 16 + lane16];
    acc = __builtin_amdgcn_mfma_f32_16x16x32_bf16(a, bu.v, acc, 0, 0, 0);
  }
#pragma unroll
  for (int r = 0; r < 4; ++r)
    cbar[(size_t)(b * 16 + quad * 4 + r) * D_ + c0 + w * 16 + lane16] = acc[r];
}

template <int K, int N, int BSTR, bool INBF, bool OUTBF, bool RELU, bool PERHEAD>
__global__ void __launch_bounds__(256) gemv8_kernel(
    const void* __restrict__ in_, const float* __restrict__ W,
    const float* __restrict__ bias, void* __restrict__ out_) {
  const int t = threadIdx.x;
  const int hoff = PERHEAD ? ((blockIdx.x * 4) >> 6) * D_ : 0;
  __shared__ u16 lsb[INBF ? 8 * K : 1];
  __shared__ float lsf[INBF ? 1 : 8 * K];
  if (INBF) {
    const u16* in = (const u16*)in_;
    const int per = 8 * K / (256 * 8);
#pragma unroll
    for (int i = 0; i < per; ++i) {
      int flat = (t + i * 256) * 8;
      int b = flat / K, k = flat % K;
      *(uint4*)&lsb[flat] = *(const uint4*)(in + (size_t)b * BSTR + hoff + k);
    }
  } else {
    const float* in = (const float*)in_;
    const int per = 8 * K / (256 * 4);
#pragma unroll
    for (int i = 0; i < per; ++i) {
      int flat = (t + i * 256) * 4;
      int b = flat / K, k = flat % K;
      *(float4*)&lsf[flat] = *(const float4*)(in + (size_t)b * BSTR + hoff + k);
    }
  }
  __syncthreads();
  const int w = t >> 6, l = t & 63;
  const int r = blockIdx.x * 4 + w;
  float acc[8] = {};
#pragma unroll
  for (int ch = 0; ch < K / 256; ++ch) {
    float4 wv = *(const float4*)(W + (size_t)r * K + ch * 256 + l * 4);
#pragma unroll
    for (int b = 0; b < 8; ++b) {
      float i0, i1, i2, i3;
      if (INBF) {
        uint2 u = *(const uint2*)&lsb[b * K + ch * 256 + l * 4];
        float2 p0 = bfpair(u.x), p1 = bfpair(u.y);
        i0 = p0.x; i1 = p0.y; i2 = p1.x; i3 = p1.y;
      } else {
        const float* p = &lsf[b * K + ch * 256 + l * 4];
        i0 = p[0]; i1 = p[1]; i2 = p[2]; i3 = p[3];
      }
      acc[b] += wv.x * i0 + wv.y * i1 + wv.z * i2 + wv.w * i3;
    }
  }
#pragma unroll
  for (int off = 32; off > 0; off >>= 1)
#pragma unroll
    for (int b = 0; b < 8; ++b) acc[b] += __shfl_down(acc[b], off, 64);
  if (l == 0) {
    const float bs = bias[r];
#pragma unroll
    for (int b = 0; b < 8; ++b) {
      float v = acc[b] + bs;
      if (RELU) v = fmaxf(v, 0.f);
      if (OUTBF) ((bf16*)out_)[(size_t)b * N + r] = __float2bfloat16(v);
      else       ((float*)out_)[(size_t)b * N + r] = v;
    }
  }
}

template <bool SECOND>
__global__ void __launch_bounds__(256) ln_kernel(
    const float* __restrict__ cls, const float* __restrict__ a,
    const float* __restrict__ bvec, const float* __restrict__ g,
    const float* __restrict__ be, float* __restrict__ out) {
  const int b = blockIdx.x, t = threadIdx.x;
  __shared__ float v[D_];
  __shared__ float red[256];
  for (int i = t; i < D_; i += 256) {
    float val;
    if (SECOND) val = a[b * D_ + i] + bvec[b * D_ + i];
    else        val = cls[i] + a[b * D_ + i];
    v[i] = val;
  }
  __syncthreads();
  float ls = 0.f;
  for (int i = t; i < D_; i += 256) ls += v[i];
  const float mean = block_sum(ls, red) * (1.f / D_);
  float lv = 0.f;
  for (int i = t; i < D_; i += 256) { float dk = v[i] - mean; lv += dk * dk; }
  const float var = block_sum(lv, red) * (1.f / D_);
  const float rs = rsqrtf(var + EPS_);
  for (int i = t; i < D_; i += 256)
    out[b * D_ + i] = (v[i] - mean) * rs * g[i] + be[i];
}

// ---------------------------------------------------------------------------
extern "C" void kernel_launch(void* const* d_in, const int* in_sizes, int n_in,
                              void* d_out, int out_size, void* d_ws, size_t ws_size,
                              hipStream_t stream) {
  (void)in_sizes; (void)n_in; (void)out_size; (void)ws_size;
  const float* x    = (const float*)d_in[0];
  const float* y    = (const float*)d_in[1];
  const float* cls  = (const float*)d_in[2];
  const float* sep  = (const float*)d_in[3];
  const float* px   = (const float*)d_in[4];
  const float* py   = (const float*)d_in[5];
  const float* Wqkv = (const float*)d_in[6];
  const float* bqkv = (const float*)d_in[7];
  const float* Wo   = (const float*)d_in[8];
  const float* bo   = (const float*)d_in[9];
  const float* W1   = (const float*)d_in[10];
  const float* b1   = (const float*)d_in[11];
  const float* W2   = (const float*)d_in[12];
  const float* b2   = (const float*)d_in[13];
  const float* g1   = (const float*)d_in[14];
  const float* be1  = (const float*)d_in[15];
  const float* g2   = (const float*)d_in[16];
  const float* be2  = (const float*)d_in[17];
  const int* xl     = (const int*)d_in[18];
  const int* yl     = (const int*)d_in[19];

  char* ws = (char*)d_ws;
  bf16*  seq   = (bf16*)(ws + OFF_SEQ);
  u16*   RT_hi = (u16*)(ws + OFF_RTHI);
  u16*   RT_lo = (u16*)(ws + OFF_RTLO);
  float* S     = (float*)(ws + OFF_S);
  u16*   P     = (u16*)(ws + OFF_P);
  float* cbar4 = (float*)(ws + OFF_CBAR);
  float* o0    = (float*)(ws + OFF_O0);
  float* att   = (float*)(ws + OFF_ATT);
  bf16*  f1    = (bf16*)(ws + OFF_F1);
  float* f2    = (float*)(ws + OFF_F2);
  u32*   bar   = (u32*)(ws + OFF_BAR);
  float* q0s   = (float*)(ws + OFF_Q0S);
  float* h0    = (float*)(ws + OFF_H0);
  float* S4    = (float*)(ws + OFF_S4);

  KP kp;
  kp.x = x; kp.y = y; kp.cls = cls; kp.sep = sep; kp.px = px; kp.py = py;
  kp.Wqkv = Wqkv; kp.bqkv = bqkv; kp.Wo = Wo; kp.bo = bo;
  kp.W1 = W1; kp.b1 = b1; kp.W2 = W2; kp.b2 = b2;
  kp.g1 = g1; kp.be1 = be1; kp.g2 = g2; kp.be2 = be2;
  kp.xl = xl; kp.yl = yl;
  kp.seq = seq; kp.RT_hi = RT_hi; kp.RT_lo = RT_lo;
  kp.S4 = S4; kp.P = P; kp.cbar4 = cbar4;
  kp.o0 = o0; kp.att = att; kp.f1 = f1; kp.f2 = f2;
  kp.out = (float*)d_out;
  kp.bar = bar;

  // Co-residency capacity check (cached). Plain launch; no cooperative API.
  static int mega_grid = -2;
  if (mega_grid == -2) {
    int nb = 0, ncu = 256;
    hipDeviceProp_t props;
    if (hipGetDeviceProperties(&props, 0) == hipSuccess)
      ncu = props.multiProcessorCount;
    if (hipOccupancyMaxActiveBlocksPerMultiprocessor(&nb, mega_kernel, 256, 0) ==
            hipSuccess && nb > 0) {
      long g = (long)nb * ncu;
      mega_grid = (int)(g < MAXGRID_ ? g : MAXGRID_);
    } else {
      mega_grid = -1;
    }
    if (mega_grid < 72) mega_grid = -1;  // P1 split needs >64 blocks
  }

  if (mega_grid > 0) {
    // zero barrier state (workspace is re-poisoned by the harness each iter)
    hipMemsetAsync(ws + OFF_BAR, 0, 4096, stream);
    mega_kernel<<<mega_grid, 256, 0, stream>>>(kp);
  } else {
    build_seq_kernel<<<MPAD_, 256, 0, stream>>>(x, y, cls, sep, px, py, xl, yl, seq);
    qproj_kernel<<<256, 256, 0, stream>>>(cls, Wqkv, bqkv, q0s);
    rproj_kernel<<<dim3(4, 16), 256, 0, stream>>>(Wqkv, q0s, RT_hi, RT_lo);
    scores_kernel<<<130, 256, 0, stream>>>(seq, RT_hi, RT_lo, xl, yl, S);
    softmax_kernel<<<dim3(16, 8), 256, 0, stream>>>(S, xl, yl, P);
    cbar_kernel<<<dim3(16, 8), 256, 0, stream>>>(seq, P, xl, yl, cbar4);
    gemv8_kernel<1024, 1024, 16384, false, false, false, true>
        <<<256, 256, 0, stream>>>(cbar4, Wqkv + (size_t)2048 * 1024, bqkv + 2048, o0);
    gemv8_kernel<1024, 1024, 1024, false, false, false, false>
        <<<256, 256, 0, stream>>>(o0, Wo, bo, att);
    ln_kernel<false><<<B_, 256, 0, stream>>>(cls, att, nullptr, g1, be1, h0);
    gemv8_kernel<1024, 2048, 1024, false, true, true, false>
        <<<512, 256, 0, stream>>>(h0, W1, b1, f1);
    gemv8_kernel<2048, 1024, 2048, true, false, false, false>
        <<<256, 256, 0, stream>>>(f1, W2, b2, f2);
    ln_kernel<true><<<B_, 256, 0, stream>>>(nullptr, h0, f2, g2, be2, (float*)d_out);
  }
}

// Round 8
// 196.318 us; speedup vs baseline: 1.1447x; 1.0276x over previous
//
#include <hip/hip_runtime.h>
#include <hip/hip_bf16.h>

#define D_ 1024
#define H_ 16
#define FF_ 2048
#define B_ 8
#define S_ 1027
#define BS_ 8216     /* B_*S_ */
#define MPAD_ 8320   /* 130 * 64 */
#define PSTR_ 1056   /* padded key stride for P */
#define EPS_ 1e-5f
#define MAXGRID_ 512
#define NTILE_ 130
#define NBUCK_ 32
#define SPC_ 133120  /* S piece stride in floats = 16*MPAD_ */

/* workspace offsets */
#define OFF_SEQ  0
#define OFF_RTHI 17039360
#define OFF_RTLO 17072128
#define OFF_S    17104896   /* fallback single S */
#define OFF_P    17637376
#define OFF_CBAR 17907712   /* 4 pieces x 524288 */
#define OFF_O0   20004864
#define OFF_ATT  20037632
#define OFF_F1   20070400
#define OFF_F2   20103168
#define OFF_BAR  20135936
#define OFF_Q0S  20140032   /* fallback only */
#define OFF_H0   20144128   /* fallback only */
#define OFF_S4   20148224   /* mega: 4 pieces x 532480 */

typedef __hip_bfloat16 bf16;
typedef unsigned short u16;
typedef unsigned int u32;
typedef __attribute__((ext_vector_type(4))) float floatx4;
typedef __bf16 bf16x8 __attribute__((ext_vector_type(8)));

__device__ __forceinline__ float2 bfpair(u32 u) {
  union { u32 u; float f; } lo, hi;
  lo.u = u << 16; hi.u = u & 0xffff0000u;
  return make_float2(lo.f, hi.f);
}

__device__ __forceinline__ u32 f2bfbits(float f) {
  union { bf16 h; u16 u; } cv; cv.h = __float2bfloat16(f); return (u32)cv.u;
}

// ---------------------------------------------------------------------------
// Write-through stores (sc0 sc1): bypass the non-coherent per-XCD L2s so data
// is globally visible at the MALL once vmcnt retires. Used for ALL inter-phase
// intermediates; makes the grid barrier fence-free (proven R3: 460->95us).
// ---------------------------------------------------------------------------
__device__ __forceinline__ void st_wt_f32(float* p, float v) {
  asm volatile("global_store_dword %0, %1, off sc0 sc1" :: "v"(p), "v"(v) : "memory");
}
__device__ __forceinline__ void st_wt_u16(u16* p, u32 v) {
  asm volatile("global_store_short %0, %1, off sc0 sc1" :: "v"(p), "v"(v) : "memory");
}
__device__ __forceinline__ void st_wt_v2(void* p, uint2 v) {
  asm volatile("global_store_dwordx2 %0, %1, off sc0 sc1" :: "v"(p), "v"(v) : "memory");
}
__device__ __forceinline__ void st_wt_f4(void* p, floatx4 v) {
  asm volatile("global_store_dwordx4 %0, %1, off sc0 sc1" :: "v"(p), "v"(v) : "memory");
}

// Fast block reductions: wave shuffle + 4-slot LDS combine.
__device__ __forceinline__ float blk_sum(float x, float* red) {
#pragma unroll
  for (int off = 32; off > 0; off >>= 1) x += __shfl_down(x, off, 64);
  __syncthreads();
  if ((threadIdx.x & 63) == 0) red[threadIdx.x >> 6] = x;
  __syncthreads();
  return red[0] + red[1] + red[2] + red[3];
}

__device__ __forceinline__ float blk_max(float x, float* red) {
#pragma unroll
  for (int off = 32; off > 0; off >>= 1) x = fmaxf(x, __shfl_down(x, off, 64));
  __syncthreads();
  if ((threadIdx.x & 63) == 0) red[threadIdx.x >> 6] = x;
  __syncthreads();
  return fmaxf(fmaxf(red[0], red[1]), fmaxf(red[2], red[3]));
}

// ---------------------------------------------------------------------------
// Fence-free grid barrier, GEN-BROADCAST form (R4/R6-proven at grid=512).
// 511 blocks poll ONE gen line; only block0 sweeps the 32 arrival buckets.
// R5's all-poll variant regressed (polling storm); R7's grid=1024 regressed
// under rocprof (2x pollers, 768 idle spinners during 256-unit phases).
// '==' safe: phase k+1 arrivals only start after gen=k is published.
// ---------------------------------------------------------------------------
__device__ __forceinline__ void gridbar(u32* bar, u32 phase) {
  asm volatile("s_waitcnt vmcnt(0) lgkmcnt(0)" ::: "memory");
  __syncthreads();
  if (threadIdx.x == 0) {
    __hip_atomic_fetch_add(bar + (blockIdx.x & (NBUCK_ - 1)) * 16, 1u,
                           __ATOMIC_RELAXED, __HIP_MEMORY_SCOPE_AGENT);
    u32* gen = bar + NBUCK_ * 16;
    if (blockIdx.x == 0) {
      const u32 target = (u32)gridDim.x * phase;
      int spins = 0;
      for (;;) {
        u32 s = 0;
#pragma unroll
        for (int i = 0; i < NBUCK_; ++i)
          s += __hip_atomic_load(bar + i * 16, __ATOMIC_RELAXED,
                                 __HIP_MEMORY_SCOPE_AGENT);
        if (s == target) break;
        __builtin_amdgcn_s_sleep(1);
        if (++spins > 300000) break;  // safety: never hang the queue
      }
      __hip_atomic_store(gen, phase, __ATOMIC_RELAXED, __HIP_MEMORY_SCOPE_AGENT);
    } else {
      int spins = 0;
      while (__hip_atomic_load(gen, __ATOMIC_RELAXED,
                               __HIP_MEMORY_SCOPE_AGENT) < phase) {
        __builtin_amdgcn_s_sleep(2);
        if (++spins > 300000) break;  // safety
      }
    }
  }
  __syncthreads();
}

struct KP {
  const float *x, *y, *cls, *sep, *px, *py;
  const float *Wqkv, *bqkv, *Wo, *bo, *W1, *b1, *W2, *b2;
  const float *g1, *be1, *g2, *be2;
  const int *xl, *yl;
  bf16* seq; u16* RT_hi; u16* RT_lo; float* S4; u16* P;
  float* cbar4; float* o0; float* att; bf16* f1; float* f2; float* out;
  u32* bar;
};

__device__ __forceinline__ const float* row_src(const KP& p, int m,
                                                const int* lx8, const int* ly8,
                                                const float** add) {
  const int b = m / S_;
  const int s = m - b * S_;
  const int lx = lx8[b], ly = ly8[b];
  *add = nullptr;
  if (s == 0) return p.cls;
  if (s <= lx) { *add = p.px; return p.x + ((size_t)b * 512 + (s - 1)) * D_; }
  if (s == lx + 1) return p.sep;
  if (s <= lx + ly + 1) { *add = p.py; return p.y + ((size_t)b * 512 + (s - lx - 2)) * D_; }
  if (s == lx + ly + 2) return p.sep;
  return nullptr;
}

// ===========================================================================
// MEGA KERNEL v8 = v6 (84us proven, grid 512) + P2 scores split into 4
// K-quarters (520 units ~ grid, 4x shorter serial MFMA chain), summed
// deterministically in P3. Grid REVERTED to 512 (R7's 1024 regressed).
// ===========================================================================
__global__ void __launch_bounds__(256, 2) mega_kernel(KP p) {
  __shared__ __align__(16) char smem_[33792];
  const int t = threadIdx.x;
  const int bid = blockIdx.x;
  const int G = gridDim.x;

  // Entry: per-block acquire fence drops stale (poisoned) cache lines before
  // this block's first workspace read. Producers store write-through, so no
  // cross-block ordering is needed for the invalidate -> no grid barrier.
  if (t == 0) __builtin_amdgcn_fence(__ATOMIC_ACQUIRE, "agent");
  __syncthreads();

  // ---- P1: rproj (inline qproj) on blocks 0..63 || build_seq (2-deep) ----
  if (bid < 64) {
    const int h = bid >> 2, cc = bid & 3;
    float* cl = (float*)smem_;
    float* qs = (float*)(smem_ + 4096);
    *(float4*)&cl[t * 4] = ((const float4*)p.cls)[t];
    __syncthreads();
    const int r = t >> 2, j = t & 3;
    const float* wr = p.Wqkv + (size_t)(h * 64 + r) * D_;
    float acc = 0.f;
#pragma unroll 8
    for (int i = 0; i < 64; ++i) {
      float4 wv = *(const float4*)(wr + i * 16 + j * 4);
      const float* c4 = &cl[i * 16 + j * 4];
      acc += wv.x * c4[0] + wv.y * c4[1] + wv.z * c4[2] + wv.w * c4[3];
    }
    acc += __shfl_xor(acc, 1, 64);
    acc += __shfl_xor(acc, 2, 64);
    if (j == 0) qs[r] = (acc + p.bqkv[h * 64 + r]) * 0.125f;
    __syncthreads();
    const int c = cc * 256 + t;
    const float* Wk = p.Wqkv + (size_t)(D_ + h * 64) * D_ + c;
    float a2 = 0.f;
#pragma unroll 8
    for (int e = 0; e < 64; ++e) a2 += Wk[(size_t)e * D_] * qs[e];
    const u32 hb = f2bfbits(a2);
    union { u32 u; float f; } hv; hv.u = hb << 16;
    st_wt_u16(p.RT_hi + h * D_ + c, hb);
    st_wt_u16(p.RT_lo + h * D_ + c, f2bfbits(a2 - hv.f));
  } else {
    int lx8[8], ly8[8];
#pragma unroll
    for (int b = 0; b < 8; ++b) { lx8[b] = p.xl[b]; ly8[b] = p.yl[b]; }
    const int stride = G - 64;
    for (int m0 = bid - 64; m0 < BS_; m0 += 2 * stride) {
      const int m1 = m0 + stride;
      const float *ad0, *ad1 = nullptr;
      const float* s0 = row_src(p, m0, lx8, ly8, &ad0);
      const float* s1 = (m1 < BS_) ? row_src(p, m1, lx8, ly8, &ad1) : nullptr;
      float4 v0, a0v, v1, a1v;
      if (s0) v0 = ((const float4*)s0)[t];
      if (ad0) a0v = ((const float4*)ad0)[t];
      if (s1) v1 = ((const float4*)s1)[t];
      if (ad1) a1v = ((const float4*)ad1)[t];
      if (s0) {
        if (ad0) { v0.x += a0v.x; v0.y += a0v.y; v0.z += a0v.z; v0.w += a0v.w; }
        uint2 o;
        o.x = f2bfbits(v0.x) | (f2bfbits(v0.y) << 16);
        o.y = f2bfbits(v0.z) | (f2bfbits(v0.w) << 16);
        st_wt_v2((u16*)p.seq + (size_t)m0 * D_ + t * 4, o);
      }
      if (s1) {
        if (ad1) { v1.x += a1v.x; v1.y += a1v.y; v1.z += a1v.z; v1.w += a1v.w; }
        uint2 o;
        o.x = f2bfbits(v1.x) | (f2bfbits(v1.y) << 16);
        o.y = f2bfbits(v1.z) | (f2bfbits(v1.w) << 16);
        st_wt_v2((u16*)p.seq + (size_t)m1 * D_ + t * 4, o);
      }
    }
  }
  gridbar(p.bar, 1);

  // ---- P2: scores, K split into 4 quarters (520 units, 8 kt each) ----
  for (int wk = bid; wk < 4 * NTILE_; wk += G) {
    const int piece = wk / NTILE_;
    const int tile = wk - piece * NTILE_;
    const int m0 = tile * 64;
    bool valid = false;
#pragma unroll
    for (int b = 0; b < B_; ++b) {
      int rs = b * S_, re = rs + p.xl[b] + p.yl[b] + 3;
      if (m0 < re && m0 + 64 > rs) valid = true;
    }
    if (!valid) continue;
    const int w = t >> 6, lane = t & 63, lane16 = lane & 15, quad = lane >> 4;
    const int row = m0 + w * 16 + lane16;
    const u16* arow = (const u16*)p.seq + (size_t)row * D_ + quad * 8;
    const u16* bh = p.RT_hi + lane16 * D_ + quad * 8;
    const u16* bl = p.RT_lo + lane16 * D_ + quad * 8;
    floatx4 acc = {};
    const int kt0 = piece * 8;
#pragma unroll
    for (int k = 0; k < 8; ++k) {
      const int kt = kt0 + k;
      bf16x8 a  = *(const bf16x8*)(arow + kt * 32);
      bf16x8 vh = *(const bf16x8*)(bh + kt * 32);
      bf16x8 vl = *(const bf16x8*)(bl + kt * 32);
      acc = __builtin_amdgcn_mfma_f32_16x16x32_bf16(a, vh, acc, 0, 0, 0);
      acc = __builtin_amdgcn_mfma_f32_16x16x32_bf16(a, vl, acc, 0, 0, 0);
    }
    st_wt_f4(&p.S4[(size_t)piece * SPC_ + (size_t)lane16 * MPAD_ + m0 + w * 16 + quad * 4], acc);
  }
  gridbar(p.bar, 2);

  // ---- P3: softmax per (h,b) over sum of 4 S pieces -> P (bf16) ----
  for (int wk = bid; wk < 128; wk += G) {
    const int h = wk >> 3, b = wk & 7;
    const int n = p.xl[b] + p.yl[b] + 3;
    float* sc = (float*)smem_;
    float* red = (float*)(smem_ + PSTR_ * 4);
    const float* Sp = p.S4 + (size_t)h * MPAD_ + b * S_;
    float lmax = -3.0e38f;
    for (int k = t; k < n; k += 256) {
      float s = Sp[k] + Sp[SPC_ + k] + Sp[2 * SPC_ + k] + Sp[3 * SPC_ + k];
      sc[k] = s;
      lmax = fmaxf(lmax, s);
    }
    const float gmax = blk_max(lmax, red);
    float lsum = 0.f;
    for (int k = t; k < n; k += 256) {
      float pr = __expf(sc[k] - gmax);
      sc[k] = pr;
      lsum += pr;
    }
    const float inv = 1.0f / blk_sum(lsum, red);
    u16* Pp = p.P + (size_t)(h * 8 + b) * PSTR_;
    for (int k = t; k < PSTR_; k += 256)
      st_wt_u16(Pp + k, (k < n) ? f2bfbits(sc[k] * inv) : 0u);
    __syncthreads();
  }
  gridbar(p.bar, 3);

  // ---- P4: cbar = P . seq via MFMA; K split 4-way into 4 buffers ----
  for (int wk = bid; wk < 512; wk += G) {
    const int ct = wk & 15, b = (wk >> 4) & 7, piece = wk >> 7;
    const int c0 = ct * 64;
    const int n = p.xl[b] + p.yl[b] + 3;
    const int nkt = (n + 31) >> 5;
    const int KR0[4] = {0, 9, 17, 25};
    const int KR1[4] = {9, 17, 25, 33};
    const int kt0 = KR0[piece];
    const int kt1 = nkt < KR1[piece] ? nkt : KR1[piece];
    u16* tile = (u16*)smem_;  // [2][32*68]
    const int w = t >> 6, lane = t & 63, lane16 = lane & 15, quad = lane >> 4;
    const int sk = t >> 3, scg = (t & 7) * 8;
    floatx4 acc = {};
    uint4 v = make_uint4(0u, 0u, 0u, 0u);
    if (kt0 < kt1 && kt0 * 32 + sk < n)
      v = *(const uint4*)((const u16*)p.seq + (size_t)((size_t)b * S_ + kt0 * 32 + sk) * D_ + c0 + scg);
    for (int kt = kt0; kt < kt1; ++kt) {
      u16* tb = tile + (kt & 1) * (32 * 68);
      *(uint2*)&tb[sk * 68 + scg]     = make_uint2(v.x, v.y);
      *(uint2*)&tb[sk * 68 + scg + 4] = make_uint2(v.z, v.w);
      v = make_uint4(0u, 0u, 0u, 0u);
      if (kt + 1 < kt1 && (kt + 1) * 32 + sk < n)
        v = *(const uint4*)((const u16*)p.seq + (size_t)((size_t)b * S_ + (kt + 1) * 32 + sk) * D_ + c0 + scg);
      __syncthreads();
      bf16x8 a = *(const bf16x8*)(p.P + (size_t)(lane16 * 8 + b) * PSTR_ + kt * 32 + quad * 8);
      union { bf16x8 v8; u16 u[8]; } bu;
#pragma unroll
      for (int j = 0; j < 8; ++j)
        bu.u[j] = tb[(quad * 8 + j) * 68 + w * 16 + lane16];
      acc = __builtin_amdgcn_mfma_f32_16x16x32_bf16(a, bu.v8, acc, 0, 0, 0);
    }
    float* dst = p.cbar4 + (size_t)piece * 131072;
#pragma unroll
    for (int r = 0; r < 4; ++r)
      st_wt_f32(&dst[(size_t)(b * 16 + quad * 4 + r) * D_ + c0 + w * 16 + lane16], acc[r]);
    __syncthreads();
  }
  gridbar(p.bar, 4);

  // ---- P5: o0 = Wv . (sum of 4 cbar pieces) + bv (per-head input slice) ----
  for (int wk = bid; wk < 256; wk += G) {
    float* lsf = (float*)smem_;
    const int hoff = ((wk * 4) >> 6) * D_;
#pragma unroll
    for (int i = 0; i < 8; ++i) {
      int flat = (t + i * 256) * 4;
      int b = flat >> 10, k = flat & 1023;
      size_t off = (size_t)b * 16384 + hoff + k;
      float4 a0 = *(const float4*)(p.cbar4 + off);
      float4 a1 = *(const float4*)(p.cbar4 + 131072 + off);
      float4 a2 = *(const float4*)(p.cbar4 + 262144 + off);
      float4 a3 = *(const float4*)(p.cbar4 + 393216 + off);
      a0.x += a1.x + a2.x + a3.x; a0.y += a1.y + a2.y + a3.y;
      a0.z += a1.z + a2.z + a3.z; a0.w += a1.w + a2.w + a3.w;
      *(float4*)&lsf[flat] = a0;
    }
    __syncthreads();
    const int w = t >> 6, l = t & 63;
    const int r = wk * 4 + w;
    const float* W = p.Wqkv + (size_t)2048 * 1024;
    float acc[8] = {};
#pragma unroll
    for (int ch = 0; ch < 4; ++ch) {
      float4 wv = *(const float4*)(W + (size_t)r * D_ + ch * 256 + l * 4);
#pragma unroll
      for (int b = 0; b < 8; ++b) {
        const float* pp = &lsf[b * D_ + ch * 256 + l * 4];
        acc[b] += wv.x * pp[0] + wv.y * pp[1] + wv.z * pp[2] + wv.w * pp[3];
      }
    }
#pragma unroll
    for (int off = 32; off > 0; off >>= 1)
#pragma unroll
      for (int b = 0; b < 8; ++b) acc[b] += __shfl_down(acc[b], off, 64);
    if (l == 0) {
      const float bs = p.bqkv[2048 + r];
#pragma unroll
      for (int b = 0; b < 8; ++b) st_wt_f32(&p.o0[(size_t)b * D_ + r], acc[b] + bs);
    }
    __syncthreads();
  }
  gridbar(p.bar, 5);

  // ---- P6: att = Wo . o0 + bo ----
  for (int wk = bid; wk < 256; wk += G) {
    float* lsf = (float*)smem_;
#pragma unroll
    for (int i = 0; i < 8; ++i) {
      int flat = (t + i * 256) * 4;
      *(float4*)&lsf[flat] = *(const float4*)(p.o0 + flat);
    }
    __syncthreads();
    const int w = t >> 6, l = t & 63;
    const int r = wk * 4 + w;
    float acc[8] = {};
#pragma unroll
    for (int ch = 0; ch < 4; ++ch) {
      float4 wv = *(const float4*)(p.Wo + (size_t)r * D_ + ch * 256 + l * 4);
#pragma unroll
      for (int b = 0; b < 8; ++b) {
        const float* pp = &lsf[b * D_ + ch * 256 + l * 4];
        acc[b] += wv.x * pp[0] + wv.y * pp[1] + wv.z * pp[2] + wv.w * pp[3];
      }
    }
#pragma unroll
    for (int off = 32; off > 0; off >>= 1)
#pragma unroll
      for (int b = 0; b < 8; ++b) acc[b] += __shfl_down(acc[b], off, 64);
    if (l == 0) {
      const float bs = p.bo[r];
#pragma unroll
      for (int b = 0; b < 8; ++b) st_wt_f32(&p.att[(size_t)b * D_ + r], acc[b] + bs);
    }
    __syncthreads();
  }
  gridbar(p.bar, 6);

  // ---- P7: f1 = relu(W1 . LN1(cls+att) + b1); LN1 computed in-block ----
  for (int wk = bid; wk < 512; wk += G) {
    float* lsf = (float*)smem_;
#pragma unroll
    for (int i = 0; i < 8; ++i) {
      int flat = (t + i * 256) * 4;
      int b = flat >> 10, k = flat & 1023;
      float4 av = *(const float4*)(p.att + (size_t)b * D_ + k);
      float4 cv = *(const float4*)(p.cls + k);
      av.x += cv.x; av.y += cv.y; av.z += cv.z; av.w += cv.w;
      *(float4*)&lsf[flat] = av;
    }
    __syncthreads();
    const int w = t >> 6, l = t & 63;
#pragma unroll
    for (int bb = 2 * w; bb < 2 * w + 2; ++bb) {
      float s = 0.f;
#pragma unroll
      for (int kk = 0; kk < 16; ++kk) s += lsf[bb * 1024 + kk * 64 + l];
#pragma unroll
      for (int off = 32; off > 0; off >>= 1) s += __shfl_xor(s, off, 64);
      const float mean = s * (1.f / D_);
      float vv = 0.f;
#pragma unroll
      for (int kk = 0; kk < 16; ++kk) {
        float d = lsf[bb * 1024 + kk * 64 + l] - mean; vv += d * d;
      }
#pragma unroll
      for (int off = 32; off > 0; off >>= 1) vv += __shfl_xor(vv, off, 64);
      const float rs = rsqrtf(vv * (1.f / D_) + EPS_);
#pragma unroll
      for (int kk = 0; kk < 16; ++kk) {
        int idx = kk * 64 + l;
        lsf[bb * 1024 + idx] =
            (lsf[bb * 1024 + idx] - mean) * rs * p.g1[idx] + p.be1[idx];
      }
    }
    __syncthreads();
    const int r = wk * 4 + w;
    float acc[8] = {};
#pragma unroll
    for (int ch = 0; ch < 4; ++ch) {
      float4 wv = *(const float4*)(p.W1 + (size_t)r * D_ + ch * 256 + l * 4);
#pragma unroll
      for (int b = 0; b < 8; ++b) {
        const float* pp = &lsf[b * D_ + ch * 256 + l * 4];
        acc[b] += wv.x * pp[0] + wv.y * pp[1] + wv.z * pp[2] + wv.w * pp[3];
      }
    }
#pragma unroll
    for (int off = 32; off > 0; off >>= 1)
#pragma unroll
      for (int b = 0; b < 8; ++b) acc[b] += __shfl_down(acc[b], off, 64);
    if (l == 0) {
      const float bs = p.b1[r];
#pragma unroll
      for (int b = 0; b < 8; ++b)
        st_wt_u16((u16*)p.f1 + (size_t)b * FF_ + r, f2bfbits(fmaxf(acc[b] + bs, 0.f)));
    }
    __syncthreads();
  }
  gridbar(p.bar, 7);

  // ---- P8: f2 = W2 . f1 + b2 (bf16 in) ----
  for (int wk = bid; wk < 256; wk += G) {
    u16* lsb = (u16*)smem_;
#pragma unroll
    for (int i = 0; i < 8; ++i) {
      int flat = (t + i * 256) * 8;
      *(uint4*)&lsb[flat] = *(const uint4*)((const u16*)p.f1 + flat);
    }
    __syncthreads();
    const int w = t >> 6, l = t & 63;
    const int r = wk * 4 + w;
    float acc[8] = {};
#pragma unroll
    for (int ch = 0; ch < 8; ++ch) {
      float4 wv = *(const float4*)(p.W2 + (size_t)r * FF_ + ch * 256 + l * 4);
#pragma unroll
      for (int b = 0; b < 8; ++b) {
        uint2 u = *(const uint2*)&lsb[b * FF_ + ch * 256 + l * 4];
        float2 p0 = bfpair(u.x), p1 = bfpair(u.y);
        acc[b] += wv.x * p0.x + wv.y * p0.y + wv.z * p1.x + wv.w * p1.y;
      }
    }
#pragma unroll
    for (int off = 32; off > 0; off >>= 1)
#pragma unroll
      for (int b = 0; b < 8; ++b) acc[b] += __shfl_down(acc[b], off, 64);
    if (l == 0) {
      const float bs = p.b2[r];
#pragma unroll
      for (int b = 0; b < 8; ++b) st_wt_f32(&p.f2[(size_t)b * D_ + r], acc[b] + bs);
    }
    __syncthreads();
  }
  gridbar(p.bar, 8);

  // ---- P9: out = LN2(LN1(cls+att) + f2)  (h0 recomputed locally) ----
  for (int wk = bid; wk < 8; wk += G) {
    float* v = (float*)smem_;
    float* red = (float*)(smem_ + D_ * 4);
    for (int i = t; i < D_; i += 256) v[i] = p.cls[i] + p.att[wk * D_ + i];
    __syncthreads();
    float ls = 0.f;
    for (int i = t; i < D_; i += 256) ls += v[i];
    const float mean1 = blk_sum(ls, red) * (1.f / D_);
    float lv = 0.f;
    for (int i = t; i < D_; i += 256) { float dk = v[i] - mean1; lv += dk * dk; }
    const float var1 = blk_sum(lv, red) * (1.f / D_);
    const float rs1 = rsqrtf(var1 + EPS_);
    for (int i = t; i < D_; i += 256) {
      float h0v = (v[i] - mean1) * rs1 * p.g1[i] + p.be1[i];
      v[i] = h0v + p.f2[wk * D_ + i];
    }
    __syncthreads();
    float ls2 = 0.f;
    for (int i = t; i < D_; i += 256) ls2 += v[i];
    const float mean2 = blk_sum(ls2, red) * (1.f / D_);
    float lv2 = 0.f;
    for (int i = t; i < D_; i += 256) { float dk = v[i] - mean2; lv2 += dk * dk; }
    const float var2 = blk_sum(lv2, red) * (1.f / D_);
    const float rs2 = rsqrtf(var2 + EPS_);
    for (int i = t; i < D_; i += 256)
      p.out[wk * D_ + i] = (v[i] - mean2) * rs2 * p.g2[i] + p.be2[i];
    __syncthreads();
  }
}

// ===========================================================================
// FALLBACK: proven 13-kernel path (used only if co-residency can't be met).
// ===========================================================================
__device__ __forceinline__ float block_sum(float x, float* red) {
  const int t = threadIdx.x;
  __syncthreads();
  red[t] = x;
  __syncthreads();
  for (int s = 128; s > 0; s >>= 1) {
    if (t < s) red[t] += red[t + s];
    __syncthreads();
  }
  return red[0];
}

__device__ __forceinline__ float block_max(float x, float* red) {
  const int t = threadIdx.x;
  __syncthreads();
  red[t] = x;
  __syncthreads();
  for (int s = 128; s > 0; s >>= 1) {
    if (t < s) red[t] = fmaxf(red[t], red[t + s]);
    __syncthreads();
  }
  return red[0];
}

__global__ void __launch_bounds__(256) build_seq_kernel(
    const float* __restrict__ x, const float* __restrict__ y,
    const float* __restrict__ cls, const float* __restrict__ sep,
    const float* __restrict__ px, const float* __restrict__ py,
    const int* __restrict__ x_len, const int* __restrict__ y_len,
    bf16* __restrict__ seq) {
  const int m = blockIdx.x, t = threadIdx.x;
  const int b = m / S_;
  const int s = m - b * S_;
  if (b >= B_) return;
  const float* src = nullptr;
  const float* add = nullptr;
  const int lx = x_len[b], ly = y_len[b];
  if (s == 0) src = cls;
  else if (s <= lx) { src = x + ((size_t)b * 512 + (s - 1)) * D_; add = px; }
  else if (s == lx + 1) src = sep;
  else if (s <= lx + ly + 1) { src = y + ((size_t)b * 512 + (s - lx - 2)) * D_; add = py; }
  else if (s == lx + ly + 2) src = sep;
  if (!src) return;
  float4 sv = ((const float4*)src)[t];
  if (add) {
    float4 av = ((const float4*)add)[t];
    sv.x += av.x; sv.y += av.y; sv.z += av.z; sv.w += av.w;
  }
  uint2 o;
  o.x = f2bfbits(sv.x) | (f2bfbits(sv.y) << 16);
  o.y = f2bfbits(sv.z) | (f2bfbits(sv.w) << 16);
  ((uint2*)(seq + (size_t)m * D_))[t] = o;
}

__global__ void __launch_bounds__(256) qproj_kernel(
    const float* __restrict__ cls, const float* __restrict__ Wqkv,
    const float* __restrict__ bqkv, float* __restrict__ q0s) {
  __shared__ float cl[D_];
  const int t = threadIdx.x;
  *(float4*)&cl[t * 4] = ((const float4*)cls)[t];
  __syncthreads();
  const int w = t >> 6, l = t & 63;
  const int r = blockIdx.x * 4 + w;
  float acc = 0.f;
#pragma unroll
  for (int ch = 0; ch < 4; ++ch) {
    float4 wv = *(const float4*)(Wqkv + (size_t)r * D_ + ch * 256 + l * 4);
    const float* c4 = &cl[ch * 256 + l * 4];
    acc += wv.x * c4[0] + wv.y * c4[1] + wv.z * c4[2] + wv.w * c4[3];
  }
#pragma unroll
  for (int off = 32; off > 0; off >>= 1) acc += __shfl_down(acc, off, 64);
  if (l == 0) q0s[r] = (acc + bqkv[r]) * 0.125f;
}

__global__ void __launch_bounds__(256) rproj_kernel(
    const float* __restrict__ Wqkv, const float* __restrict__ q0s,
    u16* __restrict__ RT_hi, u16* __restrict__ RT_lo) {
  const int h = blockIdx.y, cc = blockIdx.x, t = threadIdx.x;
  __shared__ float qs[64];
  if (t < 64) qs[t] = q0s[h * 64 + t];
  __syncthreads();
  const int c = cc * 256 + t;
  const float* Wk = Wqkv + (size_t)(D_ + h * 64) * D_ + c;
  float acc = 0.f;
#pragma unroll 8
  for (int e = 0; e < 64; ++e) acc += Wk[(size_t)e * D_] * qs[e];
  const u32 hb = f2bfbits(acc);
  union { u32 u; float f; } hv; hv.u = hb << 16;
  RT_hi[h * D_ + c] = (u16)hb;
  RT_lo[h * D_ + c] = (u16)f2bfbits(acc - hv.f);
}

__global__ void __launch_bounds__(256) scores_kernel(
    const bf16* __restrict__ seq, const u16* __restrict__ RT_hi,
    const u16* __restrict__ RT_lo, const int* __restrict__ x_len,
    const int* __restrict__ y_len, float* __restrict__ S) {
  const int m0 = blockIdx.x * 64;
  bool valid = false;
#pragma unroll
  for (int b = 0; b < B_; ++b) {
    int rs = b * S_, re = rs + x_len[b] + y_len[b] + 3;
    if (m0 < re && m0 + 64 > rs) valid = true;
  }
  if (!valid) return;
  const int t = threadIdx.x;
  const int w = t >> 6, lane = t & 63, lane16 = lane & 15, quad = lane >> 4;
  const int row = m0 + w * 16 + lane16;
  const u16* arow = (const u16*)seq + (size_t)row * D_ + quad * 8;
  const u16* bh = RT_hi + lane16 * D_ + quad * 8;
  const u16* bl = RT_lo + lane16 * D_ + quad * 8;
  floatx4 acc = {};
#pragma unroll 4
  for (int kt = 0; kt < 32; ++kt) {
    bf16x8 a  = *(const bf16x8*)(arow + kt * 32);
    bf16x8 vh = *(const bf16x8*)(bh + kt * 32);
    bf16x8 vl = *(const bf16x8*)(bl + kt * 32);
    acc = __builtin_amdgcn_mfma_f32_16x16x32_bf16(a, vh, acc, 0, 0, 0);
    acc = __builtin_amdgcn_mfma_f32_16x16x32_bf16(a, vl, acc, 0, 0, 0);
  }
  *(floatx4*)&S[(size_t)lane16 * MPAD_ + m0 + w * 16 + quad * 4] = acc;
}

__global__ void __launch_bounds__(256) softmax_kernel(
    const float* __restrict__ S, const int* __restrict__ x_len,
    const int* __restrict__ y_len, u16* __restrict__ P) {
  const int h = blockIdx.x, b = blockIdx.y, t = threadIdx.x;
  const int n = x_len[b] + y_len[b] + 3;
  __shared__ float sc[PSTR_];
  __shared__ float red[256];
  const float* Sp = S + (size_t)h * MPAD_ + b * S_;
  float lmax = -3.0e38f;
  for (int k = t; k < n; k += 256) {
    float s = Sp[k];
    sc[k] = s;
    lmax = fmaxf(lmax, s);
  }
  const float gmax = block_max(lmax, red);
  float lsum = 0.f;
  for (int k = t; k < n; k += 256) {
    float p = __expf(sc[k] - gmax);
    sc[k] = p;
    lsum += p;
  }
  const float inv = 1.0f / block_sum(lsum, red);
  u16* Pp = P + (size_t)(h * 8 + b) * PSTR_;
  for (int k = t; k < PSTR_; k += 256)
    Pp[k] = (k < n) ? (u16)f2bfbits(sc[k] * inv) : (u16)0;
}

__global__ void __launch_bounds__(256) cbar_kernel(
    const bf16* __restrict__ seq, const u16* __restrict__ P,
    const int* __restrict__ x_len, const int* __restrict__ y_len,
    float* __restrict__ cbar) {
  const int ct = blockIdx.x, b = blockIdx.y, t = threadIdx.x;
  const int c0 = ct * 64;
  const int n = x_len[b] + y_len[b] + 3;
  const int nkt = (n + 31) >> 5;
  __shared__ u16 tile[32 * 68];
  const int w = t >> 6, lane = t & 63, lane16 = lane & 15, quad = lane >> 4;
  const int sk = t >> 3, scg = (t & 7) * 8;
  floatx4 acc = {};
  for (int kt = 0; kt < nkt; ++kt) {
    const int k0 = kt * 32;
    __syncthreads();
    uint4 v = make_uint4(0u, 0u, 0u, 0u);
    if (k0 + sk < n)
      v = *(const uint4*)((const u16*)seq + (size_t)(b * S_ + k0 + sk) * D_ + c0 + scg);
    *(uint2*)&tile[sk * 68 + scg]     = make_uint2(v.x, v.y);
    *(uint2*)&tile[sk * 68 + scg + 4] = make_uint2(v.z, v.w);
    __syncthreads();
    bf16x8 a = *(const bf16x8*)(P + (size_t)(lane16 * 8 + b) * PSTR_ + k0 + quad * 8);
    union { bf16x8 v; u16 u[8]; } bu;
#pragma unroll
    for (int j = 0; j < 8; ++j)
      bu.u[j] = tile[(quad * 8 + j) * 68 + w * 16 + lane16];
    acc = __builtin_amdgcn_mfma_f32_16x16x32_bf16(a, bu.v, acc, 0, 0, 0);
  }
#pragma unroll
  for (int r = 0; r < 4; ++r)
    cbar[(size_t)(b * 16 + quad * 4 + r) * D_ + c0 + w * 16 + lane16] = acc[r];
}

template <int K, int N, int BSTR, bool INBF, bool OUTBF, bool RELU, bool PERHEAD>
__global__ void __launch_bounds__(256) gemv8_kernel(
    const void* __restrict__ in_, const float* __restrict__ W,
    const float* __restrict__ bias, void* __restrict__ out_) {
  const int t = threadIdx.x;
  const int hoff = PERHEAD ? ((blockIdx.x * 4) >> 6) * D_ : 0;
  __shared__ u16 lsb[INBF ? 8 * K : 1];
  __shared__ float lsf[INBF ? 1 : 8 * K];
  if (INBF) {
    const u16* in = (const u16*)in_;
    const int per = 8 * K / (256 * 8);
#pragma unroll
    for (int i = 0; i < per; ++i) {
      int flat = (t + i * 256) * 8;
      int b = flat / K, k = flat % K;
      *(uint4*)&lsb[flat] = *(const uint4*)(in + (size_t)b * BSTR + hoff + k);
    }
  } else {
    const float* in = (const float*)in_;
    const int per = 8 * K / (256 * 4);
#pragma unroll
    for (int i = 0; i < per; ++i) {
      int flat = (t + i * 256) * 4;
      int b = flat / K, k = flat % K;
      *(float4*)&lsf[flat] = *(const float4*)(in + (size_t)b * BSTR + hoff + k);
    }
  }
  __syncthreads();
  const int w = t >> 6, l = t & 63;
  const int r = blockIdx.x * 4 + w;
  float acc[8] = {};
#pragma unroll
  for (int ch = 0; ch < K / 256; ++ch) {
    float4 wv = *(const float4*)(W + (size_t)r * K + ch * 256 + l * 4);
#pragma unroll
    for (int b = 0; b < 8; ++b) {
      float i0, i1, i2, i3;
      if (INBF) {
        uint2 u = *(const uint2*)&lsb[b * K + ch * 256 + l * 4];
        float2 p0 = bfpair(u.x), p1 = bfpair(u.y);
        i0 = p0.x; i1 = p0.y; i2 = p1.x; i3 = p1.y;
      } else {
        const float* p = &lsf[b * K + ch * 256 + l * 4];
        i0 = p[0]; i1 = p[1]; i2 = p[2]; i3 = p[3];
      }
      acc[b] += wv.x * i0 + wv.y * i1 + wv.z * i2 + wv.w * i3;
    }
  }
#pragma unroll
  for (int off = 32; off > 0; off >>= 1)
#pragma unroll
    for (int b = 0; b < 8; ++b) acc[b] += __shfl_down(acc[b], off, 64);
  if (l == 0) {
    const float bs = bias[r];
#pragma unroll
    for (int b = 0; b < 8; ++b) {
      float v = acc[b] + bs;
      if (RELU) v = fmaxf(v, 0.f);
      if (OUTBF) ((bf16*)out_)[(size_t)b * N + r] = __float2bfloat16(v);
      else       ((float*)out_)[(size_t)b * N + r] = v;
    }
  }
}

template <bool SECOND>
__global__ void __launch_bounds__(256) ln_kernel(
    const float* __restrict__ cls, const float* __restrict__ a,
    const float* __restrict__ bvec, const float* __restrict__ g,
    const float* __restrict__ be, float* __restrict__ out) {
  const int b = blockIdx.x, t = threadIdx.x;
  __shared__ float v[D_];
  __shared__ float red[256];
  for (int i = t; i < D_; i += 256) {
    float val;
    if (SECOND) val = a[b * D_ + i] + bvec[b * D_ + i];
    else        val = cls[i] + a[b * D_ + i];
    v[i] = val;
  }
  __syncthreads();
  float ls = 0.f;
  for (int i = t; i < D_; i += 256) ls += v[i];
  const float mean = block_sum(ls, red) * (1.f / D_);
  float lv = 0.f;
  for (int i = t; i < D_; i += 256) { float dk = v[i] - mean; lv += dk * dk; }
  const float var = block_sum(lv, red) * (1.f / D_);
  const float rs = rsqrtf(var + EPS_);
  for (int i = t; i < D_; i += 256)
    out[b * D_ + i] = (v[i] - mean) * rs * g[i] + be[i];
}

// ---------------------------------------------------------------------------
extern "C" void kernel_launch(void* const* d_in, const int* in_sizes, int n_in,
                              void* d_out, int out_size, void* d_ws, size_t ws_size,
                              hipStream_t stream) {
  (void)in_sizes; (void)n_in; (void)out_size; (void)ws_size;
  const float* x    = (const float*)d_in[0];
  const float* y    = (const float*)d_in[1];
  const float* cls  = (const float*)d_in[2];
  const float* sep  = (const float*)d_in[3];
  const float* px   = (const float*)d_in[4];
  const float* py   = (const float*)d_in[5];
  const float* Wqkv = (const float*)d_in[6];
  const float* bqkv = (const float*)d_in[7];
  const float* Wo   = (const float*)d_in[8];
  const float* bo   = (const float*)d_in[9];
  const float* W1   = (const float*)d_in[10];
  const float* b1   = (const float*)d_in[11];
  const float* W2   = (const float*)d_in[12];
  const float* b2   = (const float*)d_in[13];
  const float* g1   = (const float*)d_in[14];
  const float* be1  = (const float*)d_in[15];
  const float* g2   = (const float*)d_in[16];
  const float* be2  = (const float*)d_in[17];
  const int* xl     = (const int*)d_in[18];
  const int* yl     = (const int*)d_in[19];

  char* ws = (char*)d_ws;
  bf16*  seq   = (bf16*)(ws + OFF_SEQ);
  u16*   RT_hi = (u16*)(ws + OFF_RTHI);
  u16*   RT_lo = (u16*)(ws + OFF_RTLO);
  float* S     = (float*)(ws + OFF_S);
  u16*   P     = (u16*)(ws + OFF_P);
  float* cbar4 = (float*)(ws + OFF_CBAR);
  float* o0    = (float*)(ws + OFF_O0);
  float* att   = (float*)(ws + OFF_ATT);
  bf16*  f1    = (bf16*)(ws + OFF_F1);
  float* f2    = (float*)(ws + OFF_F2);
  u32*   bar   = (u32*)(ws + OFF_BAR);
  float* q0s   = (float*)(ws + OFF_Q0S);
  float* h0    = (float*)(ws + OFF_H0);
  float* S4    = (float*)(ws + OFF_S4);

  KP kp;
  kp.x = x; kp.y = y; kp.cls = cls; kp.sep = sep; kp.px = px; kp.py = py;
  kp.Wqkv = Wqkv; kp.bqkv = bqkv; kp.Wo = Wo; kp.bo = bo;
  kp.W1 = W1; kp.b1 = b1; kp.W2 = W2; kp.b2 = b2;
  kp.g1 = g1; kp.be1 = be1; kp.g2 = g2; kp.be2 = be2;
  kp.xl = xl; kp.yl = yl;
  kp.seq = seq; kp.RT_hi = RT_hi; kp.RT_lo = RT_lo;
  kp.S4 = S4; kp.P = P; kp.cbar4 = cbar4;
  kp.o0 = o0; kp.att = att; kp.f1 = f1; kp.f2 = f2;
  kp.out = (float*)d_out;
  kp.bar = bar;

  // Co-residency capacity check (cached). Plain launch; no cooperative API.
  static int mega_grid = -2;
  if (mega_grid == -2) {
    int nb = 0, ncu = 256;
    hipDeviceProp_t props;
    if (hipGetDeviceProperties(&props, 0) == hipSuccess)
      ncu = props.multiProcessorCount;
    if (hipOccupancyMaxActiveBlocksPerMultiprocessor(&nb, mega_kernel, 256, 0) ==
            hipSuccess && nb > 0) {
      long g = (long)nb * ncu;
      mega_grid = (int)(g < MAXGRID_ ? g : MAXGRID_);
    } else {
      mega_grid = -1;
    }
    if (mega_grid < 72) mega_grid = -1;  // P1 split needs >64 blocks
  }

  if (mega_grid > 0) {
    // zero barrier state (workspace is re-poisoned by the harness each iter)
    hipMemsetAsync(ws + OFF_BAR, 0, 4096, stream);
    mega_kernel<<<mega_grid, 256, 0, stream>>>(kp);
  } else {
    build_seq_kernel<<<MPAD_, 256, 0, stream>>>(x, y, cls, sep, px, py, xl, yl, seq);
    qproj_kernel<<<256, 256, 0, stream>>>(cls, Wqkv, bqkv, q0s);
    rproj_kernel<<<dim3(4, 16), 256, 0, stream>>>(Wqkv, q0s, RT_hi, RT_lo);
    scores_kernel<<<130, 256, 0, stream>>>(seq, RT_hi, RT_lo, xl, yl, S);
    softmax_kernel<<<dim3(16, 8), 256, 0, stream>>>(S, xl, yl, P);
    cbar_kernel<<<dim3(16, 8), 256, 0, stream>>>(seq, P, xl, yl, cbar4);
    gemv8_kernel<1024, 1024, 16384, false, false, false, true>
        <<<256, 256, 0, stream>>>(cbar4, Wqkv + (size_t)2048 * 1024, bqkv + 2048, o0);
    gemv8_kernel<1024, 1024, 1024, false, false, false, false>
        <<<256, 256, 0, stream>>>(o0, Wo, bo, att);
    ln_kernel<false><<<B_, 256, 0, stream>>>(cls, att, nullptr, g1, be1, h0);
    gemv8_kernel<1024, 2048, 1024, false, true, true, false>
        <<<512, 256, 0, stream>>>(h0, W1, b1, f1);
    gemv8_kernel<2048, 1024, 2048, true, false, false, false>
        <<<256, 256, 0, stream>>>(f1, W2, b2, f2);
    ln_kernel<true><<<B_, 256, 0, stream>>>(nullptr, h0, f2, g2, be2, (float*)d_out);
  }
}